// Round 1
// baseline (17631.145 us; speedup 1.0000x reference)
//
#include <hip/hip_runtime.h>
#include <hip/hip_bf16.h>

// ---------------- problem dims ----------------
#define NB 128      // batch
#define SLEN 1024
#define NSENT 64
#define QLEN 64
#define ED 50
#define RD 400      // RNN units
#define MD 300      // memory size
#define VD 2000     // vocab

typedef short short8 __attribute__((ext_vector_type(8)));
typedef float f32x4 __attribute__((ext_vector_type(4)));

__device__ __forceinline__ f32x4 MFMA(short8 a, short8 b, f32x4 c) {
  return __builtin_amdgcn_mfma_f32_16x16x32_bf16(a, b, c, 0, 0, 0);
}
__device__ __forceinline__ float sigm(float x) { return 1.f / (1.f + __expf(-x)); }
__device__ __forceinline__ float tanh_f(float x) {
  x = fminf(fmaxf(x, -15.f), 15.f);
  float e = __expf(2.f * x);
  return (e - 1.f) / (e + 1.f);
}
__device__ __forceinline__ short f2bf(float v) {
  __hip_bfloat16 h = __float2bfloat16(v);
  return *reinterpret_cast<short*>(&h);
}

// ---------------- workspace layout (bytes) ----------------
// all offsets multiples of 512
#define OFF_CNT      0u                    // 4096 B of u32 counters
#define OFF_MASK     4096u                 // [128][1024] u64 = 1,048,576
#define OFF_ITAB     1052672u              // [1024][1200] f32 = 4,915,200
#define OFF_QTAB     5967872u              // [64][1200] f32 = 307,200
#define OFF_EINFO    6275072u              // [128][64][400] f32 = 13,107,200
#define OFF_EQ       19382272u             // [128][400] f32 = 204,800
#define OFF_PROD     19587072u             // [128][64][416] bf16 = 6,815,744
#define OFF_HIDDEN   26402816u             // [128][64][320] bf16 = 5,242,880
#define OFF_HA       31645696u             // [128][416] bf16 = 106,496
#define OFF_HB       31752192u
#define OFF_HMA      31858688u             // [128][320] bf16 = 81,920
#define OFF_HMB      31940608u
#define OFF_HANS     32022528u             // [128][2048] bf16 = 524,288
#define OFF_PART     32546816u             // [250][128] f32 = 128,000
#define OFF_STOT     32674816u             // 128 f32
#define WS_NEED      32675840u

// ---------------- barriers ----------------
// monotonic-counter sense-free barrier; requires all participating WGs resident
// (all scan grids <=256 WGs with >80KB LDS => 1 WG/CU => guaranteed).
__device__ __forceinline__ void grp_barrier(unsigned* cnt, unsigned nw, unsigned epoch) {
  __syncthreads();
  if (threadIdx.x == 0) {
    __threadfence();  // release: make this WG's stores visible (L2 wb)
    __hip_atomic_fetch_add(cnt, 1u, __ATOMIC_RELAXED, __HIP_MEMORY_SCOPE_AGENT);
    while (__hip_atomic_load(cnt, __ATOMIC_RELAXED, __HIP_MEMORY_SCOPE_AGENT) < nw * epoch)
      __builtin_amdgcn_s_sleep(1);
    __threadfence();  // acquire: invalidate stale cached lines
  }
  __syncthreads();
}

// hierarchical barrier for 250 WGs: 25 sub-counters (10 each) -> master (+25/epoch)
__device__ __forceinline__ void ans_barrier(unsigned* subs, unsigned* master, unsigned epoch) {
  __syncthreads();
  if (threadIdx.x == 0) {
    __threadfence();
    unsigned old = __hip_atomic_fetch_add(&subs[blockIdx.x / 10], 1u,
                                          __ATOMIC_RELAXED, __HIP_MEMORY_SCOPE_AGENT);
    if ((old % 10u) == 9u)
      __hip_atomic_fetch_add(master, 1u, __ATOMIC_RELAXED, __HIP_MEMORY_SCOPE_AGENT);
    while (__hip_atomic_load(master, __ATOMIC_RELAXED, __HIP_MEMORY_SCOPE_AGENT) < 25u * epoch)
      __builtin_amdgcn_s_sleep(1);
    __threadfence();
  }
  __syncthreads();
}

// ---------------- prep kernels ----------------
// xz tables: table[tok][c] = b0[c] + sum_e emb[tok][e]*W[e][c]
__global__ void build_tables(const float* __restrict__ info_emb, const float* __restrict__ Wi,
                             const float* __restrict__ bi, const float* __restrict__ q_emb,
                             const float* __restrict__ Wq, const float* __restrict__ bq,
                             float* __restrict__ itab, float* __restrict__ qtab) {
  int idx = blockIdx.x * 256 + threadIdx.x;
  const int N1 = SLEN * 1200;
  if (idx < N1) {
    int r = idx / 1200, c = idx - r * 1200;
    float s = bi[c];
    for (int e = 0; e < ED; ++e) s += info_emb[r * ED + e] * Wi[e * 1200 + c];
    itab[idx] = s;
  } else {
    int i2 = idx - N1;  // < 64*1200 by grid sizing
    int r = i2 / 1200, c = i2 - r * 1200;
    float s = bq[c];
    for (int e = 0; e < ED; ++e) s += q_emb[r * ED + e] * Wq[e * 1200 + c];
    qtab[i2] = s;
  }
}

__global__ void build_mask(const int* __restrict__ info_idx, unsigned long long* __restrict__ mask) {
  int idx = blockIdx.x * 256 + threadIdx.x;  // 128*64
  int b = idx >> 6, j = idx & 63;
  int t = info_idx[idx];
  atomicOr(&mask[(b << 10) + t], 1ull << j);
}

__global__ void k_prod(const float* __restrict__ enc_info, const float* __restrict__ enc_q,
                       const int* __restrict__ num_sent, __hip_bfloat16* __restrict__ prod) {
  int idx = blockIdx.x * 256 + threadIdx.x;  // 128*64*416
  int b = idx / (64 * 416);
  int r = idx - b * (64 * 416);
  int j = r / 416, k = r - j * 416;
  float v = 0.f;
  if (k < RD && j <= num_sent[b]) v = enc_info[(b * 64 + j) * RD + k] * enc_q[b * RD + k];
  prod[idx] = __float2bfloat16(v);
}

// ---------------- scan: info / question GRU (H=400) ----------------
// grid 80 = 8 batch-groups x 10 WGs; WG owns 40 hidden dims; block 192 (3 waves)
// wave w: gate-aligned N-tiles (z: cols 16w, r: 48+16w, h: 96+16w) of LDS Ut[144][424]
template <int STEPS, int IS_INFO>
__global__ __launch_bounds__(192) void scan_table(
    const int* __restrict__ toks, const float* __restrict__ table, const float* __restrict__ U,
    const float* __restrict__ b1, const unsigned long long* __restrict__ mask,
    const int* __restrict__ qidx, float* __restrict__ enc, __hip_bfloat16* __restrict__ hA,
    __hip_bfloat16* __restrict__ hB, unsigned* __restrict__ cnt) {
  __shared__ short Ut[144 * 424];
  const int g = blockIdx.x / 10, wgin = blockIdx.x % 10;
  const int bb = g * 16, dimbase = wgin * 40;

  for (int idx = threadIdx.x; idx < 144 * 416; idx += 192) {
    int c = idx / 416, k = idx - c * 416;
    int gate = c / 48, cl = c - gate * 48;
    float v = 0.f;
    if (cl < 40 && k < RD) v = U[k * 1200 + gate * RD + dimbase + cl];
    Ut[c * 424 + k] = f2bf(v);
  }
  for (int idx = threadIdx.x; idx < 16 * 40; idx += 192) {
    int r = bb + idx / 40, c2 = dimbase + idx % 40;
    hA[r * 416 + c2] = __float2bfloat16(0.f);
    hB[r * 416 + c2] = __float2bfloat16(0.f);
  }
  if (wgin == 9)
    for (int idx = threadIdx.x; idx < 16 * 16; idx += 192) {
      int r = bb + idx / 16, c2 = 400 + idx % 16;
      hA[r * 416 + c2] = __float2bfloat16(0.f);
      hB[r * 416 + c2] = __float2bfloat16(0.f);
    }
  grp_barrier(cnt + g, 10, 1);

  const int lane = threadIdx.x & 63, wid = threadIdx.x >> 6;
  const int c = lane & 15, g4 = lane >> 4;
  const int dl = wid * 16 + c;
  const bool valid = dl < 40;
  const int dim = dimbase + dl;
  float b1z = 0, b1r = 0, b1h = 0;
  if (valid) { b1z = b1[dim]; b1r = b1[RD + dim]; b1h = b1[2 * RD + dim]; }
  int rows[4], qm1[4];
  float hreg[4] = {0.f, 0.f, 0.f, 0.f};
#pragma unroll
  for (int i = 0; i < 4; ++i) {
    rows[i] = bb + g4 * 4 + i;
    if (!IS_INFO) qm1[i] = qidx[rows[i]] - 1;
  }

  for (int t = 0; t < STEPS; ++t) {
    const __hip_bfloat16* cur = (t & 1) ? hB : hA;
    __hip_bfloat16* nxt = (t & 1) ? hA : hB;
    f32x4 az = {0,0,0,0}, ar = {0,0,0,0}, ah = {0,0,0,0};
    const short* arow = (const short*)cur + (bb + c) * 416 + g4 * 8;
    const int bcol = wid * 16 + c, koff = g4 * 8;
#pragma unroll
    for (int kk = 0; kk < 13; ++kk) {
      short8 a = *(const short8*)(arow + kk * 32);
      short8 vz = *(const short8*)(&Ut[(bcol) * 424 + kk * 32 + koff]);
      short8 vr = *(const short8*)(&Ut[(48 + bcol) * 424 + kk * 32 + koff]);
      short8 vh = *(const short8*)(&Ut[(96 + bcol) * 424 + kk * 32 + koff]);
      az = MFMA(a, vz, az);
      ar = MFMA(a, vr, ar);
      ah = MFMA(a, vh, ah);
    }
#pragma unroll
    for (int i = 0; i < 4; ++i) {
      int m = rows[i];
      float xz = 0, xr = 0, xh = 0;
      if (valid) {
        int tok = toks[m * STEPS + t];
        const float* trow = table + tok * 1200;
        xz = trow[dim]; xr = trow[RD + dim]; xh = trow[2 * RD + dim];
      }
      float z = sigm(az[i] + xz + b1z);
      float rr = sigm(ar[i] + xr + b1r);
      float hh = tanh_f(xh + rr * (ah[i] + b1h));
      float hn = z * hreg[i] + (1.f - z) * hh;
      hreg[i] = hn;
      if (valid) {
        nxt[m * 416 + dim] = __float2bfloat16(hn);
        if (IS_INFO) {
          unsigned long long mk = mask[((unsigned)m << 10) + t];
          while (mk) {
            int j = __builtin_ctzll(mk);
            mk &= mk - 1;
            enc[(m * 64 + j) * RD + dim] = hn;
          }
        } else if (t == qm1[i]) {
          enc[m * RD + dim] = hn;
        }
      }
    }
    grp_barrier(cnt + g, 10, t + 2);
  }
}

// ---------------- scan: memory GRU (H=300, input prod K=416) ----------------
// grid 80 = 8 groups x 10 WGs; WG owns 30 dims; block 128 (2 waves)
__global__ __launch_bounds__(128) void scan_mem(
    const __hip_bfloat16* __restrict__ prod, const float* __restrict__ Um,
    const float* __restrict__ Wm, const float* __restrict__ bm, const int* __restrict__ num_sent,
    __hip_bfloat16* __restrict__ hidden, __hip_bfloat16* __restrict__ hA,
    __hip_bfloat16* __restrict__ hB, unsigned* __restrict__ cnt) {
  __shared__ short Ut[96 * 328];
  __shared__ short Wt[96 * 424];
  const int g = blockIdx.x / 10, wgin = blockIdx.x % 10;
  const int bb = g * 16, dimbase = wgin * 30;

  for (int idx = threadIdx.x; idx < 96 * 320; idx += 128) {
    int c = idx / 320, k = idx - c * 320;
    int gate = c / 32, cl = c - gate * 32;
    float v = 0.f;
    if (cl < 30 && k < MD) v = Um[k * 900 + gate * MD + dimbase + cl];
    Ut[c * 328 + k] = f2bf(v);
  }
  for (int idx = threadIdx.x; idx < 96 * 416; idx += 128) {
    int c = idx / 416, k = idx - c * 416;
    int gate = c / 32, cl = c - gate * 32;
    float v = 0.f;
    if (cl < 30 && k < RD) v = Wm[k * 900 + gate * MD + dimbase + cl];
    Wt[c * 424 + k] = f2bf(v);
  }
  for (int idx = threadIdx.x; idx < 16 * 30; idx += 128) {
    int r = bb + idx / 30, c2 = dimbase + idx % 30;
    hA[r * 320 + c2] = __float2bfloat16(0.f);
    hB[r * 320 + c2] = __float2bfloat16(0.f);
  }
  if (wgin == 9)
    for (int idx = threadIdx.x; idx < 16 * 20; idx += 128) {
      int r = bb + idx / 20, c2 = 300 + idx % 20;
      hA[r * 320 + c2] = __float2bfloat16(0.f);
      hB[r * 320 + c2] = __float2bfloat16(0.f);
    }
  grp_barrier(cnt + g, 10, 1);

  const int lane = threadIdx.x & 63, wid = threadIdx.x >> 6;
  const int c = lane & 15, g4 = lane >> 4;
  const int dl = wid * 16 + c;
  const bool valid = dl < 30;
  const int dim = dimbase + dl;
  float cbz = 0, cbr = 0, b0h = 0, b1h = 0;
  if (valid) {
    cbz = bm[dim] + bm[900 + dim];
    cbr = bm[MD + dim] + bm[900 + MD + dim];
    b0h = bm[2 * MD + dim];
    b1h = bm[900 + 2 * MD + dim];
  }
  int rows[4], ns[4];
  float hreg[4] = {0.f, 0.f, 0.f, 0.f};
#pragma unroll
  for (int i = 0; i < 4; ++i) {
    rows[i] = bb + g4 * 4 + i;
    ns[i] = num_sent[rows[i]];
  }

  for (int t = 0; t < 64; ++t) {
    const __hip_bfloat16* cur = (t & 1) ? hB : hA;
    __hip_bfloat16* nxt = (t & 1) ? hA : hB;
    f32x4 az = {0,0,0,0}, ar = {0,0,0,0}, arh = {0,0,0,0}, axh = {0,0,0,0};
    const int bcol = wid * 16 + c, koff = g4 * 8;
    const short* hrow = (const short*)cur + (bb + c) * 320 + koff;
#pragma unroll
    for (int kk = 0; kk < 10; ++kk) {
      short8 a = *(const short8*)(hrow + kk * 32);
      az = MFMA(a, *(const short8*)(&Ut[(bcol) * 328 + kk * 32 + koff]), az);
      ar = MFMA(a, *(const short8*)(&Ut[(32 + bcol) * 328 + kk * 32 + koff]), ar);
      arh = MFMA(a, *(const short8*)(&Ut[(64 + bcol) * 328 + kk * 32 + koff]), arh);
    }
    const short* xrow = (const short*)prod + (bb + c) * (64 * 416) + t * 416 + koff;
#pragma unroll
    for (int kx = 0; kx < 13; ++kx) {
      short8 a = *(const short8*)(xrow + kx * 32);
      az = MFMA(a, *(const short8*)(&Wt[(bcol) * 424 + kx * 32 + koff]), az);
      ar = MFMA(a, *(const short8*)(&Wt[(32 + bcol) * 424 + kx * 32 + koff]), ar);
      axh = MFMA(a, *(const short8*)(&Wt[(64 + bcol) * 424 + kx * 32 + koff]), axh);
    }
#pragma unroll
    for (int i = 0; i < 4; ++i) {
      float z = sigm(az[i] + cbz);
      float rr = sigm(ar[i] + cbr);
      float hh = tanh_f(axh[i] + b0h + rr * (arh[i] + b1h));
      float hn = z * hreg[i] + (1.f - z) * hh;
      hreg[i] = hn;
      if (valid) {
        int m = rows[i];
        nxt[m * 320 + dim] = __float2bfloat16(hn);
        hidden[(m * 64 + t) * 320 + dim] =
            (t <= ns[i]) ? __float2bfloat16(hn) : __float2bfloat16(0.f);
      }
    }
    grp_barrier(cnt + g, 10, t + 2);
  }
}

// ---------------- scan: answer GRU (H=2000, softmax candidate) ----------------
// grid 250 WGs x 512 threads; WG owns 8 dims; LDS Ut[32][2056] (z8|r8|h8|pad8), Wt[32][328]
__global__ __launch_bounds__(512) void scan_ans(
    const __hip_bfloat16* __restrict__ hidden, const float* __restrict__ Ua,
    const float* __restrict__ Wa, const float* __restrict__ ba, float* __restrict__ out,
    __hip_bfloat16* __restrict__ hAns, float* __restrict__ partials, float* __restrict__ stot,
    unsigned* __restrict__ subs, unsigned* __restrict__ master) {
  __shared__ short Ut[32 * 2056];
  __shared__ short Wt[32 * 328];
  const int w = blockIdx.x;
  const int wbase = w * 8;

  for (int idx = threadIdx.x; idx < 32 * 2048; idx += 512) {
    int c = idx / 2048, k = idx - c * 2048;
    int sel = c >> 3, cl = c & 7;
    float v = 0.f;
    if (sel < 3 && k < VD) v = Ua[k * 6000 + sel * VD + wbase + cl];
    Ut[c * 2056 + k] = f2bf(v);
  }
  for (int idx = threadIdx.x; idx < 32 * 320; idx += 512) {
    int c = idx / 320, k = idx - c * 320;
    int sel = c >> 3, cl = c & 7;
    float v = 0.f;
    if (sel < 3 && k < MD) v = Wa[k * 6000 + sel * VD + wbase + cl];
    Wt[c * 328 + k] = f2bf(v);
  }
  for (int idx = threadIdx.x; idx < 128 * 8; idx += 512)
    hAns[(idx / 8) * 2048 + wbase + (idx & 7)] = __float2bfloat16(0.f);
  if (w == 249)
    for (int idx = threadIdx.x; idx < 128 * 48; idx += 512)
      hAns[(idx / 48) * 2048 + 2000 + idx % 48] = __float2bfloat16(0.f);
  ans_barrier(subs, master, 1);
  unsigned ep = 2;

  const int lane = threadIdx.x & 63, wid = threadIdx.x >> 6;
  const int c = lane & 15, g4 = lane >> 4;
  const bool zlane = c < 8;
  const int dim = wbase + (c & 7);
  float cbz = 0, cbr = 0, b0h = 0, b1h = 0;
  if (zlane) {
    cbz = ba[dim] + ba[6000 + dim];
    cbr = ba[VD + dim] + ba[6000 + VD + dim];
    b0h = ba[2 * VD + dim];
    b1h = ba[6000 + 2 * VD + dim];
  }
  int rows[4];
  float hreg[4] = {0.f, 0.f, 0.f, 0.f};
#pragma unroll
  for (int i = 0; i < 4; ++i) rows[i] = wid * 16 + g4 * 4 + i;

  for (int t = 0; t < 64; ++t) {
    f32x4 azr = {0,0,0,0}, arh = {0,0,0,0}, axh = {0,0,0,0};
    const int koff = g4 * 8;
    const short* hrow = (const short*)hAns + (wid * 16 + c) * 2048 + koff;
#pragma unroll 8
    for (int kk = 0; kk < 64; ++kk) {
      short8 a = *(const short8*)(hrow + kk * 32);
      azr = MFMA(a, *(const short8*)(&Ut[c * 2056 + kk * 32 + koff]), azr);
      arh = MFMA(a, *(const short8*)(&Ut[(16 + c) * 2056 + kk * 32 + koff]), arh);
    }
    const short* xrow = (const short*)hidden + (wid * 16 + c) * (64 * 320) + t * 320 + koff;
#pragma unroll
    for (int kx = 0; kx < 10; ++kx) {
      short8 a = *(const short8*)(xrow + kx * 32);
      azr = MFMA(a, *(const short8*)(&Wt[c * 328 + kx * 32 + koff]), azr);
      axh = MFMA(a, *(const short8*)(&Wt[(16 + c) * 328 + kx * 32 + koff]), axh);
    }
    float z4[4], ee[4], er[4];
#pragma unroll
    for (int i = 0; i < 4; ++i) {
      float rzv = __shfl_xor(azr[i], 8, 64);  // r-gate value for z-lanes
      float z = sigm(azr[i] + cbz);
      float rr = sigm(rzv + cbr);
      float lg = (axh[i] + b0h) + rr * (arh[i] + b1h);
      float e = zlane ? __expf(lg) : 0.f;
      z4[i] = z; ee[i] = e; er[i] = e;
    }
#pragma unroll
    for (int d = 1; d <= 4; d <<= 1)
#pragma unroll
      for (int i = 0; i < 4; ++i) er[i] += __shfl_xor(er[i], d, 64);
    if (c == 0) {
      float4 p4 = make_float4(er[0], er[1], er[2], er[3]);
      *(float4*)&partials[w * 128 + wid * 16 + g4 * 4] = p4;
    }
    ans_barrier(subs, master, ep++);  // A: partials ready
    if (w < 8) {
      int b2 = w * 16 + (threadIdx.x >> 5);
      int ch = threadIdx.x & 31;
      float s = 0.f;
      for (int w2 = ch; w2 < 250; w2 += 32) s += partials[w2 * 128 + b2];
#pragma unroll
      for (int d = 1; d <= 16; d <<= 1) s += __shfl_xor(s, d, 64);
      if (ch == 0) stot[b2] = s;
    }
    ans_barrier(subs, master, ep++);  // B: totals ready
#pragma unroll
    for (int i = 0; i < 4; ++i) {
      float S = stot[rows[i]];
      float hh = ee[i] / S;
      float hn = z4[i] * hreg[i] + (1.f - z4[i]) * hh;
      hreg[i] = hn;
      if (zlane) {
        hAns[rows[i] * 2048 + dim] = __float2bfloat16(hn);
        out[(rows[i] * 64 + t) * VD + dim] = hn;
      }
    }
    ans_barrier(subs, master, ep++);  // C: h updated
  }
}

// ---------------- launch ----------------
extern "C" void kernel_launch(void* const* d_in, const int* in_sizes, int n_in, void* d_out,
                              int out_size, void* d_ws, size_t ws_size, hipStream_t stream) {
  (void)in_sizes; (void)n_in; (void)out_size;
  if (ws_size < (size_t)WS_NEED) return;  // fail loudly via wrong output

  const int* info = (const int*)d_in[0];
  const int* info_idx = (const int*)d_in[1];
  const int* num_sent = (const int*)d_in[2];
  const int* question = (const int*)d_in[3];
  const int* qidx = (const int*)d_in[4];
  const float* info_emb = (const float*)d_in[5];
  const float* Wi = (const float*)d_in[6];
  const float* Ui = (const float*)d_in[7];
  const float* bi = (const float*)d_in[8];
  const float* q_emb = (const float*)d_in[9];
  const float* Wq = (const float*)d_in[10];
  const float* Uq = (const float*)d_in[11];
  const float* bq = (const float*)d_in[12];
  const float* Wm = (const float*)d_in[13];
  const float* Um = (const float*)d_in[14];
  const float* bm = (const float*)d_in[15];
  const float* Wa = (const float*)d_in[16];
  const float* Ua = (const float*)d_in[17];
  const float* ba = (const float*)d_in[18];

  char* ws = (char*)d_ws;
  unsigned* cnt = (unsigned*)(ws + OFF_CNT);
  unsigned long long* mask = (unsigned long long*)(ws + OFF_MASK);
  float* itab = (float*)(ws + OFF_ITAB);
  float* qtab = (float*)(ws + OFF_QTAB);
  float* enc_info = (float*)(ws + OFF_EINFO);
  float* enc_q = (float*)(ws + OFF_EQ);
  __hip_bfloat16* prod = (__hip_bfloat16*)(ws + OFF_PROD);
  __hip_bfloat16* hidden = (__hip_bfloat16*)(ws + OFF_HIDDEN);
  __hip_bfloat16* hA = (__hip_bfloat16*)(ws + OFF_HA);
  __hip_bfloat16* hB = (__hip_bfloat16*)(ws + OFF_HB);
  __hip_bfloat16* hMA = (__hip_bfloat16*)(ws + OFF_HMA);
  __hip_bfloat16* hMB = (__hip_bfloat16*)(ws + OFF_HMB);
  __hip_bfloat16* hAns = (__hip_bfloat16*)(ws + OFF_HANS);
  float* partials = (float*)(ws + OFF_PART);
  float* stot = (float*)(ws + OFF_STOT);

  // zero barrier counters + mask; zero hidden (pad cols / masked rows stay 0)
  hipMemsetAsync(ws + OFF_CNT, 0, OFF_ITAB, stream);
  hipMemsetAsync(ws + OFF_HIDDEN, 0, 128 * 64 * 320 * 2, stream);

  build_tables<<<5100, 256, 0, stream>>>(info_emb, Wi, bi, q_emb, Wq, bq, itab, qtab);
  build_mask<<<32, 256, 0, stream>>>(info_idx, mask);
  scan_table<1024, 1><<<80, 192, 0, stream>>>(info, itab, Ui, bi + 1200, mask, nullptr, enc_info,
                                              hA, hB, cnt + 0);
  scan_table<64, 0><<<80, 192, 0, stream>>>(question, qtab, Uq, bq + 1200, nullptr, qidx, enc_q,
                                            hA, hB, cnt + 8);
  k_prod<<<13312, 256, 0, stream>>>(enc_info, enc_q, num_sent, prod);
  scan_mem<<<80, 128, 0, stream>>>(prod, Um, Wm, bm, num_sent, hidden, hMA, hMB, cnt + 16);
  scan_ans<<<250, 512, 0, stream>>>(hidden, Ua, Wa, ba, (float*)d_out, hAns, partials, stot,
                                    cnt + 24, cnt + 49);
}

// Round 3
// 11650.363 us; speedup vs baseline: 1.5134x; 1.5134x over previous
//
#include <hip/hip_runtime.h>
#include <hip/hip_bf16.h>

// ---------------- problem dims ----------------
#define NB 128
#define SLEN 1024
#define NSENT 64
#define QLEN 64
#define ED 50
#define RD 400
#define MD 300
#define VD 2000

typedef short short8 __attribute__((ext_vector_type(8)));
typedef float f32x4 __attribute__((ext_vector_type(4)));

__device__ __forceinline__ f32x4 MFMA(short8 a, short8 b, f32x4 c) {
  return __builtin_amdgcn_mfma_f32_16x16x32_bf16(a, b, c, 0, 0, 0);
}
__device__ __forceinline__ float sigm(float x) { return 1.f / (1.f + __expf(-x)); }
__device__ __forceinline__ float tanh_f(float x) {
  x = fminf(fmaxf(x, -15.f), 15.f);
  float e = __expf(2.f * x);
  return (e - 1.f) / (e + 1.f);
}
__device__ __forceinline__ short f2bf(float v) {
  __hip_bfloat16 h = __float2bfloat16(v);
  return *reinterpret_cast<short*>(&h);
}

// ---------------- workspace layout (bytes) ----------------
// counters: u32 slot i at byte OFF_CNT + i*256 (one cache line each)
//   info groups: slots 0..7 ; q groups: 8..15 ; mem groups: 16..23
//   ans subs: 24..48 ; ans master: 49 ; ans relay flags: 50..74
#define OFF_CNT     0u          // 20480 B
#define OFF_PART    20480u      // [128][256] f32 = 131072
#define OFF_MASK    151552u     // [128][1024] u64 = 1048576
#define OFF_ITAB    1200128u    // [1024][1200] f32 = 4915200
#define OFF_QTAB    6115328u    // [64][1200] f32 = 307200
#define OFF_EINFO   6422528u    // [128][64][400] f32 = 13107200
#define OFF_EQ      19529728u   // [128][400] f32 = 204800
#define OFF_PROD    19734528u   // [128][64][416] bf16 = 6815744
#define OFF_HIDDEN  26550272u   // [128][64][320] bf16 = 5242880
#define OFF_SCRA    31793152u   // union scratch (see below)
#define WS_NEED     32317440u
// scratch union (sequential kernels):
//   fused scan: hA=+0, hB=+106496, hQA=+212992, hQB=+319488  (each [128][416] bf16)
//   scan_mem:   hMA=+0, hMB=+81920                            (each [128][320] bf16)
//   scan_ans:   hAns=+0                                       ([128][2048] bf16)

// ---------------- barriers ----------------
// monotonic-counter barrier; cnt points at a PRIVATE 256B-padded slot.
__device__ __forceinline__ void grp_barrier(unsigned* cnt, unsigned nw, unsigned epoch) {
  __syncthreads();
  if (threadIdx.x == 0) {
    __threadfence();  // release
    __hip_atomic_fetch_add(cnt, 1u, __ATOMIC_RELAXED, __HIP_MEMORY_SCOPE_AGENT);
    while (__hip_atomic_load(cnt, __ATOMIC_RELAXED, __HIP_MEMORY_SCOPE_AGENT) < nw * epoch)
      __builtin_amdgcn_s_sleep(1);
    __threadfence();  // acquire
  }
  __syncthreads();
}

// 250-WG hierarchical barrier with leader relay (bounds per-line pollers):
// 25 subs (10 WGs each, padded lines) -> master (+25/epoch);
// sub-leader polls master then posts relay flag; members poll relay.
__device__ __forceinline__ void ans_barrier(unsigned* cnt32, unsigned epoch) {
  __syncthreads();
  if (threadIdx.x == 0) {
    const unsigned sub = blockIdx.x / 10;
    __threadfence();  // release
    unsigned old = __hip_atomic_fetch_add(&cnt32[(24 + sub) * 64], 1u,
                                          __ATOMIC_RELAXED, __HIP_MEMORY_SCOPE_AGENT);
    if ((old % 10u) == 9u)
      __hip_atomic_fetch_add(&cnt32[49 * 64], 1u, __ATOMIC_RELAXED, __HIP_MEMORY_SCOPE_AGENT);
    if (blockIdx.x % 10 == 0) {
      while (__hip_atomic_load(&cnt32[49 * 64], __ATOMIC_RELAXED, __HIP_MEMORY_SCOPE_AGENT) <
             25u * epoch)
        __builtin_amdgcn_s_sleep(1);
      __hip_atomic_store(&cnt32[(50 + sub) * 64], epoch, __ATOMIC_RELAXED,
                         __HIP_MEMORY_SCOPE_AGENT);
    } else {
      while (__hip_atomic_load(&cnt32[(50 + sub) * 64], __ATOMIC_RELAXED,
                               __HIP_MEMORY_SCOPE_AGENT) < epoch)
        __builtin_amdgcn_s_sleep(1);
    }
    __threadfence();  // acquire
  }
  __syncthreads();
}

// ---------------- prep kernels ----------------
__global__ void build_tables(const float* __restrict__ info_emb, const float* __restrict__ Wi,
                             const float* __restrict__ bi, const float* __restrict__ q_emb,
                             const float* __restrict__ Wq, const float* __restrict__ bq,
                             float* __restrict__ itab, float* __restrict__ qtab) {
  int idx = blockIdx.x * 256 + threadIdx.x;
  const int N1 = SLEN * 1200;
  if (idx < N1) {
    int r = idx / 1200, c = idx - r * 1200;
    float s = bi[c];
    for (int e = 0; e < ED; ++e) s += info_emb[r * ED + e] * Wi[e * 1200 + c];
    itab[idx] = s;
  } else {
    int i2 = idx - N1;
    int r = i2 / 1200, c = i2 - r * 1200;
    float s = bq[c];
    for (int e = 0; e < ED; ++e) s += q_emb[r * ED + e] * Wq[e * 1200 + c];
    qtab[i2] = s;
  }
}

__global__ void build_mask(const int* __restrict__ info_idx, unsigned long long* __restrict__ mask) {
  int idx = blockIdx.x * 256 + threadIdx.x;  // 128*64
  int b = idx >> 6, j = idx & 63;
  int t = info_idx[idx];
  atomicOr(&mask[(b << 10) + t], 1ull << j);
}

__global__ void k_prod(const float* __restrict__ enc_info, const float* __restrict__ enc_q,
                       const int* __restrict__ num_sent, __hip_bfloat16* __restrict__ prod) {
  int idx = blockIdx.x * 256 + threadIdx.x;  // 128*64*416
  int b = idx / (64 * 416);
  int r = idx - b * (64 * 416);
  int j = r / 416, k = r - j * 416;
  float v = 0.f;
  if (k < RD && j <= num_sent[b]) v = enc_info[(b * 64 + j) * RD + k] * enc_q[b * RD + k];
  prod[idx] = __float2bfloat16(v);
}

// ---------------- fused info+question GRU scan (H=400) ----------------
// blocks 0..79: info (1024 steps, groups g=bid%8 XCD-local, wgin=bid/8)
// blocks 80..159: question (64 steps), same structure, separate buffers/counters
__global__ __launch_bounds__(192) void scan_rnn(
    const int* __restrict__ info, const float* __restrict__ itab, const float* __restrict__ Ui,
    const float* __restrict__ bi1, const unsigned long long* __restrict__ mask,
    float* __restrict__ enc_info, const int* __restrict__ question,
    const float* __restrict__ qtab, const float* __restrict__ Uq, const float* __restrict__ bq1,
    const int* __restrict__ qidx, float* __restrict__ enc_q, __hip_bfloat16* __restrict__ hA,
    __hip_bfloat16* __restrict__ hB, __hip_bfloat16* __restrict__ hQA,
    __hip_bfloat16* __restrict__ hQB, unsigned* __restrict__ cnt32) {
  __shared__ short Ut[144 * 424];
  const bool isq = blockIdx.x >= 80;
  const int bid = isq ? blockIdx.x - 80 : blockIdx.x;
  const int g = bid & 7, wgin = bid >> 3;
  const int steps = isq ? 64 : 1024;
  const int* toks = isq ? question : info;
  const float* table = isq ? qtab : itab;
  const float* U = isq ? Uq : Ui;
  const float* b1 = isq ? bq1 : bi1;
  float* enc = isq ? enc_q : enc_info;
  __hip_bfloat16* bufA = isq ? hQA : hA;
  __hip_bfloat16* bufB = isq ? hQB : hB;
  unsigned* cnt = cnt32 + (isq ? (8 + g) : g) * 64;
  const int bb = g * 16, dimbase = wgin * 40;

  for (int idx = threadIdx.x; idx < 144 * 416; idx += 192) {
    int c = idx / 416, k = idx - c * 416;
    int gate = c / 48, cl = c - gate * 48;
    float v = 0.f;
    if (cl < 40 && k < RD) v = U[k * 1200 + gate * RD + dimbase + cl];
    Ut[c * 424 + k] = f2bf(v);
  }
  for (int idx = threadIdx.x; idx < 16 * 40; idx += 192) {
    int r = bb + idx / 40, c2 = dimbase + idx % 40;
    bufA[r * 416 + c2] = __float2bfloat16(0.f);
    bufB[r * 416 + c2] = __float2bfloat16(0.f);
  }
  if (wgin == 9)
    for (int idx = threadIdx.x; idx < 16 * 16; idx += 192) {
      int r = bb + idx / 16, c2 = 400 + idx % 16;
      bufA[r * 416 + c2] = __float2bfloat16(0.f);
      bufB[r * 416 + c2] = __float2bfloat16(0.f);
    }
  grp_barrier(cnt, 10, 1);

  const int lane = threadIdx.x & 63, wid = threadIdx.x >> 6;
  const int c = lane & 15, g4 = lane >> 4;
  const int dl = wid * 16 + c;
  const bool valid = dl < 40;
  const int dim = dimbase + dl;
  float b1z = 0, b1r = 0, b1h = 0;
  if (valid) { b1z = b1[dim]; b1r = b1[RD + dim]; b1h = b1[2 * RD + dim]; }
  int rows[4], qm1[4];
  float hreg[4] = {0.f, 0.f, 0.f, 0.f};
#pragma unroll
  for (int i = 0; i < 4; ++i) {
    rows[i] = bb + g4 * 4 + i;
    qm1[i] = isq ? (qidx[rows[i]] - 1) : -1;
  }

  for (int t = 0; t < steps; ++t) {
    const __hip_bfloat16* cur = (t & 1) ? bufB : bufA;
    __hip_bfloat16* nxt = (t & 1) ? bufA : bufB;
    f32x4 az = {0,0,0,0}, ar = {0,0,0,0}, ah = {0,0,0,0};
    const short* arow = (const short*)cur + (bb + c) * 416 + g4 * 8;
    const int bcol = wid * 16 + c, koff = g4 * 8;
#pragma unroll
    for (int kk = 0; kk < 13; ++kk) {
      short8 a = *(const short8*)(arow + kk * 32);
      short8 vz = *(const short8*)(&Ut[(bcol) * 424 + kk * 32 + koff]);
      short8 vr = *(const short8*)(&Ut[(48 + bcol) * 424 + kk * 32 + koff]);
      short8 vh = *(const short8*)(&Ut[(96 + bcol) * 424 + kk * 32 + koff]);
      az = MFMA(a, vz, az);
      ar = MFMA(a, vr, ar);
      ah = MFMA(a, vh, ah);
    }
#pragma unroll
    for (int i = 0; i < 4; ++i) {
      int m = rows[i];
      float xz = 0, xr = 0, xh = 0;
      if (valid) {
        int tok = toks[m * steps + t];
        const float* trow = table + tok * 1200;
        xz = trow[dim]; xr = trow[RD + dim]; xh = trow[2 * RD + dim];
      }
      float z = sigm(az[i] + xz + b1z);
      float rr = sigm(ar[i] + xr + b1r);
      float hh = tanh_f(xh + rr * (ah[i] + b1h));
      float hn = z * hreg[i] + (1.f - z) * hh;
      hreg[i] = hn;
      if (valid) {
        nxt[m * 416 + dim] = __float2bfloat16(hn);
        if (!isq) {
          unsigned long long mk = mask[((unsigned)m << 10) + t];
          while (mk) {
            int j = __builtin_ctzll(mk);
            mk &= mk - 1;
            enc[(m * 64 + j) * RD + dim] = hn;
          }
        } else if (t == qm1[i]) {
          enc[m * RD + dim] = hn;
        }
      }
    }
    grp_barrier(cnt, 10, t + 2);
  }
}

// ---------------- memory GRU (H=300, input prod K=416) ----------------
__global__ __launch_bounds__(128) void scan_mem(
    const __hip_bfloat16* __restrict__ prod, const float* __restrict__ Um,
    const float* __restrict__ Wm, const float* __restrict__ bm, const int* __restrict__ num_sent,
    __hip_bfloat16* __restrict__ hidden, __hip_bfloat16* __restrict__ hA,
    __hip_bfloat16* __restrict__ hB, unsigned* __restrict__ cnt32) {
  __shared__ short Ut[96 * 328];
  __shared__ short Wt[96 * 424];
  const int g = blockIdx.x & 7, wgin = blockIdx.x >> 3;
  unsigned* cnt = cnt32 + (16 + g) * 64;
  const int bb = g * 16, dimbase = wgin * 30;

  for (int idx = threadIdx.x; idx < 96 * 320; idx += 128) {
    int c = idx / 320, k = idx - c * 320;
    int gate = c / 32, cl = c - gate * 32;
    float v = 0.f;
    if (cl < 30 && k < MD) v = Um[k * 900 + gate * MD + dimbase + cl];
    Ut[c * 328 + k] = f2bf(v);
  }
  for (int idx = threadIdx.x; idx < 96 * 416; idx += 128) {
    int c = idx / 416, k = idx - c * 416;
    int gate = c / 32, cl = c - gate * 32;
    float v = 0.f;
    if (cl < 30 && k < RD) v = Wm[k * 900 + gate * MD + dimbase + cl];
    Wt[c * 424 + k] = f2bf(v);
  }
  for (int idx = threadIdx.x; idx < 16 * 30; idx += 128) {
    int r = bb + idx / 30, c2 = dimbase + idx % 30;
    hA[r * 320 + c2] = __float2bfloat16(0.f);
    hB[r * 320 + c2] = __float2bfloat16(0.f);
  }
  if (wgin == 9)
    for (int idx = threadIdx.x; idx < 16 * 20; idx += 128) {
      int r = bb + idx / 20, c2 = 300 + idx % 20;
      hA[r * 320 + c2] = __float2bfloat16(0.f);
      hB[r * 320 + c2] = __float2bfloat16(0.f);
    }
  grp_barrier(cnt, 10, 1);

  const int lane = threadIdx.x & 63, wid = threadIdx.x >> 6;
  const int c = lane & 15, g4 = lane >> 4;
  const int dl = wid * 16 + c;
  const bool valid = dl < 30;
  const int dim = dimbase + dl;
  float cbz = 0, cbr = 0, b0h = 0, b1h = 0;
  if (valid) {
    cbz = bm[dim] + bm[900 + dim];
    cbr = bm[MD + dim] + bm[900 + MD + dim];
    b0h = bm[2 * MD + dim];
    b1h = bm[900 + 2 * MD + dim];
  }
  int rows[4], ns[4];
  float hreg[4] = {0.f, 0.f, 0.f, 0.f};
#pragma unroll
  for (int i = 0; i < 4; ++i) {
    rows[i] = bb + g4 * 4 + i;
    ns[i] = num_sent[rows[i]];
  }

  for (int t = 0; t < 64; ++t) {
    const __hip_bfloat16* cur = (t & 1) ? hB : hA;
    __hip_bfloat16* nxt = (t & 1) ? hA : hB;
    f32x4 az = {0,0,0,0}, ar = {0,0,0,0}, arh = {0,0,0,0}, axh = {0,0,0,0};
    const int bcol = wid * 16 + c, koff = g4 * 8;
    const short* hrow = (const short*)cur + (bb + c) * 320 + koff;
#pragma unroll
    for (int kk = 0; kk < 10; ++kk) {
      short8 a = *(const short8*)(hrow + kk * 32);
      az = MFMA(a, *(const short8*)(&Ut[(bcol) * 328 + kk * 32 + koff]), az);
      ar = MFMA(a, *(const short8*)(&Ut[(32 + bcol) * 328 + kk * 32 + koff]), ar);
      arh = MFMA(a, *(const short8*)(&Ut[(64 + bcol) * 328 + kk * 32 + koff]), arh);
    }
    const short* xrow = (const short*)prod + (bb + c) * (64 * 416) + t * 416 + koff;
#pragma unroll
    for (int kx = 0; kx < 13; ++kx) {
      short8 a = *(const short8*)(xrow + kx * 32);
      az = MFMA(a, *(const short8*)(&Wt[(bcol) * 424 + kx * 32 + koff]), az);
      ar = MFMA(a, *(const short8*)(&Wt[(32 + bcol) * 424 + kx * 32 + koff]), ar);
      axh = MFMA(a, *(const short8*)(&Wt[(64 + bcol) * 424 + kx * 32 + koff]), axh);
    }
#pragma unroll
    for (int i = 0; i < 4; ++i) {
      float z = sigm(az[i] + cbz);
      float rr = sigm(ar[i] + cbr);
      float hh = tanh_f(axh[i] + b0h + rr * (arh[i] + b1h));
      float hn = z * hreg[i] + (1.f - z) * hh;
      hreg[i] = hn;
      if (valid) {
        int m = rows[i];
        nxt[m * 320 + dim] = __float2bfloat16(hn);
        hidden[(m * 64 + t) * 320 + dim] =
            (t <= ns[i]) ? __float2bfloat16(hn) : __float2bfloat16(0.f);
      }
    }
    grp_barrier(cnt, 10, t + 2);
  }
}

// ---------------- answer GRU (H=2000, softmax candidate) ----------------
// 250 WGs x 512 thr; WG owns 8 cols; 2 barriers/step (partials-ready, h-ready);
// every WG reduces the [128][256] transposed partials for its own rows.
__global__ __launch_bounds__(512) void scan_ans(
    const __hip_bfloat16* __restrict__ hidden, const float* __restrict__ Ua,
    const float* __restrict__ Wa, const float* __restrict__ ba, float* __restrict__ out,
    __hip_bfloat16* __restrict__ hAns, float* __restrict__ partials,
    unsigned* __restrict__ cnt32) {
  __shared__ short Ut[32 * 2056];
  __shared__ short Wt[32 * 328];
  const int w = blockIdx.x;
  const int wbase = w * 8;

  for (int idx = threadIdx.x; idx < 32 * 2048; idx += 512) {
    int c = idx / 2048, k = idx - c * 2048;
    int sel = c >> 3, cl = c & 7;
    float v = 0.f;
    if (sel < 3 && k < VD) v = Ua[k * 6000 + sel * VD + wbase + cl];
    Ut[c * 2056 + k] = f2bf(v);
  }
  for (int idx = threadIdx.x; idx < 32 * 320; idx += 512) {
    int c = idx / 320, k = idx - c * 320;
    int sel = c >> 3, cl = c & 7;
    float v = 0.f;
    if (sel < 3 && k < MD) v = Wa[k * 6000 + sel * VD + wbase + cl];
    Wt[c * 328 + k] = f2bf(v);
  }
  for (int idx = threadIdx.x; idx < 128 * 8; idx += 512)
    hAns[(idx / 8) * 2048 + wbase + (idx & 7)] = __float2bfloat16(0.f);
  if (w == 249)
    for (int idx = threadIdx.x; idx < 128 * 48; idx += 512)
      hAns[(idx / 48) * 2048 + 2000 + idx % 48] = __float2bfloat16(0.f);
  ans_barrier(cnt32, 1);
  unsigned ep = 2;

  const int lane = threadIdx.x & 63, wid = threadIdx.x >> 6;
  const int c = lane & 15, g4 = lane >> 4;
  const bool zlane = c < 8;
  const int dim = wbase + (c & 7);
  float cbz = 0, cbr = 0, b0h = 0, b1h = 0;
  if (zlane) {
    cbz = ba[dim] + ba[6000 + dim];
    cbr = ba[VD + dim] + ba[6000 + VD + dim];
    b0h = ba[2 * VD + dim];
    b1h = ba[6000 + 2 * VD + dim];
  }
  int rows[4];
  float hreg[4] = {0.f, 0.f, 0.f, 0.f};
#pragma unroll
  for (int i = 0; i < 4; ++i) rows[i] = wid * 16 + g4 * 4 + i;

  for (int t = 0; t < 64; ++t) {
    f32x4 azr = {0,0,0,0}, arh = {0,0,0,0}, axh = {0,0,0,0};
    const int koff = g4 * 8;
    const short* hrow = (const short*)hAns + (wid * 16 + c) * 2048 + koff;
#pragma unroll 8
    for (int kk = 0; kk < 64; ++kk) {
      short8 a = *(const short8*)(hrow + kk * 32);
      azr = MFMA(a, *(const short8*)(&Ut[c * 2056 + kk * 32 + koff]), azr);
      arh = MFMA(a, *(const short8*)(&Ut[(16 + c) * 2056 + kk * 32 + koff]), arh);
    }
    const short* xrow = (const short*)hidden + (wid * 16 + c) * (64 * 320) + t * 320 + koff;
#pragma unroll
    for (int kx = 0; kx < 10; ++kx) {
      short8 a = *(const short8*)(xrow + kx * 32);
      azr = MFMA(a, *(const short8*)(&Wt[c * 328 + kx * 32 + koff]), azr);
      axh = MFMA(a, *(const short8*)(&Wt[(16 + c) * 328 + kx * 32 + koff]), axh);
    }
    float z4[4], ee[4], er[4];
#pragma unroll
    for (int i = 0; i < 4; ++i) {
      float rzv = __shfl_xor(azr[i], 8, 64);  // r-gate partial for z-lanes
      float z = sigm(azr[i] + cbz);
      float rr = sigm(rzv + cbr);
      float lg = (axh[i] + b0h) + rr * (arh[i] + b1h);
      float e = zlane ? __expf(lg) : 0.f;
      z4[i] = z; ee[i] = e; er[i] = e;
    }
#pragma unroll
    for (int d = 1; d <= 4; d <<= 1)
#pragma unroll
      for (int i = 0; i < 4; ++i) er[i] += __shfl_xor(er[i], d, 64);
    if (c == 0) {
#pragma unroll
      for (int i = 0; i < 4; ++i) partials[rows[i] * 256 + w] = er[i];
    }
    ans_barrier(cnt32, ep++);  // A: partials ready
    float T4[4];
#pragma unroll
    for (int i = 0; i < 4; ++i) {
      const float4* pr = (const float4*)(partials + rows[i] * 256 + c * 16);
      float s = 0.f;
#pragma unroll
      for (int k = 0; k < 4; ++k) { float4 v = pr[k]; s += v.x + v.y + v.z + v.w; }
#pragma unroll
      for (int d = 1; d <= 8; d <<= 1) s += __shfl_xor(s, d, 16);
      T4[i] = s;
    }
#pragma unroll
    for (int i = 0; i < 4; ++i) {
      float hh = ee[i] / T4[i];
      float hn = z4[i] * hreg[i] + (1.f - z4[i]) * hh;
      hreg[i] = hn;
      if (zlane) {
        hAns[rows[i] * 2048 + dim] = __float2bfloat16(hn);
        out[(rows[i] * 64 + t) * VD + dim] = hn;
      }
    }
    ans_barrier(cnt32, ep++);  // C: h ready for next step
  }
}

// ---------------- launch ----------------
extern "C" void kernel_launch(void* const* d_in, const int* in_sizes, int n_in, void* d_out,
                              int out_size, void* d_ws, size_t ws_size, hipStream_t stream) {
  (void)in_sizes; (void)n_in; (void)out_size;
  if (ws_size < (size_t)WS_NEED) return;

  const int* info = (const int*)d_in[0];
  const int* info_idx = (const int*)d_in[1];
  const int* num_sent = (const int*)d_in[2];
  const int* question = (const int*)d_in[3];
  const int* qidx = (const int*)d_in[4];
  const float* info_emb = (const float*)d_in[5];
  const float* Wi = (const float*)d_in[6];
  const float* Ui = (const float*)d_in[7];
  const float* bi = (const float*)d_in[8];
  const float* q_emb = (const float*)d_in[9];
  const float* Wq = (const float*)d_in[10];
  const float* Uq = (const float*)d_in[11];
  const float* bq = (const float*)d_in[12];
  const float* Wm = (const float*)d_in[13];
  const float* Um = (const float*)d_in[14];
  const float* bm = (const float*)d_in[15];
  const float* Wa = (const float*)d_in[16];
  const float* Ua = (const float*)d_in[17];
  const float* ba = (const float*)d_in[18];

  char* ws = (char*)d_ws;
  unsigned* cnt32 = (unsigned*)(ws + OFF_CNT);
  float* partials = (float*)(ws + OFF_PART);
  unsigned long long* mask = (unsigned long long*)(ws + OFF_MASK);
  float* itab = (float*)(ws + OFF_ITAB);
  float* qtab = (float*)(ws + OFF_QTAB);
  float* enc_info = (float*)(ws + OFF_EINFO);
  float* enc_q = (float*)(ws + OFF_EQ);
  __hip_bfloat16* prod = (__hip_bfloat16*)(ws + OFF_PROD);
  __hip_bfloat16* hidden = (__hip_bfloat16*)(ws + OFF_HIDDEN);
  __hip_bfloat16* hA = (__hip_bfloat16*)(ws + OFF_SCRA);
  __hip_bfloat16* hB = (__hip_bfloat16*)(ws + OFF_SCRA + 106496);
  __hip_bfloat16* hQA = (__hip_bfloat16*)(ws + OFF_SCRA + 212992);
  __hip_bfloat16* hQB = (__hip_bfloat16*)(ws + OFF_SCRA + 319488);
  __hip_bfloat16* hMA = (__hip_bfloat16*)(ws + OFF_SCRA);
  __hip_bfloat16* hMB = (__hip_bfloat16*)(ws + OFF_SCRA + 81920);
  __hip_bfloat16* hAns = (__hip_bfloat16*)(ws + OFF_SCRA);

  // zero counters + partials + mask; zero hidden (pad cols stay 0)
  hipMemsetAsync(ws, 0, OFF_ITAB, stream);
  hipMemsetAsync(ws + OFF_HIDDEN, 0, 128 * 64 * 320 * 2, stream);

  build_tables<<<5100, 256, 0, stream>>>(info_emb, Wi, bi, q_emb, Wq, bq, itab, qtab);
  build_mask<<<32, 256, 0, stream>>>(info_idx, mask);
  scan_rnn<<<160, 192, 0, stream>>>(info, itab, Ui, bi + 1200, mask, enc_info, question, qtab,
                                    Uq, bq + 1200, qidx, enc_q, hA, hB, hQA, hQB, cnt32);
  k_prod<<<13312, 256, 0, stream>>>(enc_info, enc_q, num_sent, prod);
  scan_mem<<<80, 128, 0, stream>>>(prod, Um, Wm, bm, num_sent, hidden, hMA, hMB, cnt32);
  scan_ans<<<250, 512, 0, stream>>>(hidden, Ua, Wa, ba, (float*)d_out, hAns, partials, cnt32);
}

// Round 4
// 10207.259 us; speedup vs baseline: 1.7273x; 1.1414x over previous
//
#include <hip/hip_runtime.h>
#include <hip/hip_bf16.h>

// ---------------- problem dims ----------------
#define NB 128
#define SLEN 1024
#define NSENT 64
#define QLEN 64
#define ED 50
#define RD 400
#define MD 300
#define VD 2000

typedef short short8 __attribute__((ext_vector_type(8)));
typedef float f32x4 __attribute__((ext_vector_type(4)));

union U16 { struct { unsigned long long lo, hi; } q; short8 s; };

__device__ __forceinline__ f32x4 MFMA(short8 a, short8 b, f32x4 c) {
  return __builtin_amdgcn_mfma_f32_16x16x32_bf16(a, b, c, 0, 0, 0);
}
__device__ __forceinline__ float sigm(float x) { return 1.f / (1.f + __expf(-x)); }
__device__ __forceinline__ float tanh_f(float x) {
  x = fminf(fmaxf(x, -15.f), 15.f);
  float e = __expf(2.f * x);
  return (e - 1.f) / (e + 1.f);
}
__device__ __forceinline__ short f2bf(float v) {
  __hip_bfloat16 h = __float2bfloat16(v);
  return *reinterpret_cast<short*>(&h);
}
__device__ __forceinline__ unsigned long long ld_coh64(const void* p) {
  return __hip_atomic_load((const unsigned long long*)p, __ATOMIC_RELAXED,
                           __HIP_MEMORY_SCOPE_AGENT);
}
__device__ __forceinline__ void st_coh64(void* p, unsigned long long v) {
  __hip_atomic_store((unsigned long long*)p, v, __ATOMIC_RELAXED, __HIP_MEMORY_SCOPE_AGENT);
}
__device__ __forceinline__ void st_coh32(void* p, unsigned v) {
  __hip_atomic_store((unsigned*)p, v, __ATOMIC_RELAXED, __HIP_MEMORY_SCOPE_AGENT);
}

// ---------------- workspace layout (bytes) ----------------
// counters: u32 slot i at byte OFF_CNT + i*256 (one cache line each)
//   info groups: slots 0..7 ; q groups: 8..15 ; mem groups: 16..23
//   ans subs: 24..48 ; ans master: 49 ; ans relay flags: 50..74
#define OFF_CNT     0u          // 20480
#define OFF_PART    20480u      // [128][256] f32 = 131072
#define OFF_MASK    151552u     // [128][1024] u64 = 1048576
#define OFF_ITAB    1200128u    // [1024][1200] f32 = 4915200
#define OFF_QTAB    6115328u    // [64][1200] f32 = 307200
#define OFF_EINFO   6422528u    // [128][64][400] bf16 = 6553600
#define OFF_EQ      12976128u   // [128][400] f32 = 204800
#define OFF_PROD    13180928u   // [128][64][416] bf16 = 6815744
#define OFF_HIDDEN  19996672u   // [128][64][320] bf16 = 5242880
#define OFF_HA      25239552u   // [128][416] bf16 = 106496
#define OFF_HB      25346048u
#define OFF_HQA     25452544u
#define OFF_HQB     25559040u
#define OFF_HMA     25665536u   // [128][320] bf16 = 81920
#define OFF_HMB     25747456u
#define OFF_HANS    25829376u   // [128][2048] bf16 = 524288
#define WS_NEED     26353664u

// ---------------- barriers (no cache fences; exchanged data is device-coherent) ----
__device__ __forceinline__ void grp_barrier(unsigned* cnt, unsigned nw, unsigned epoch) {
  asm volatile("s_waitcnt vmcnt(0)" ::: "memory");  // each wave: coherent stores acked
  __syncthreads();
  if (threadIdx.x == 0) {
    __hip_atomic_fetch_add(cnt, 1u, __ATOMIC_RELAXED, __HIP_MEMORY_SCOPE_AGENT);
    while (__hip_atomic_load(cnt, __ATOMIC_RELAXED, __HIP_MEMORY_SCOPE_AGENT) < nw * epoch)
      __builtin_amdgcn_s_sleep(1);
  }
  __syncthreads();
}

// 250-WG hierarchical barrier with leader relay; same monotonic-counter scheme.
__device__ __forceinline__ void ans_barrier(unsigned* cnt32, unsigned epoch) {
  asm volatile("s_waitcnt vmcnt(0)" ::: "memory");
  __syncthreads();
  if (threadIdx.x == 0) {
    const unsigned sub = blockIdx.x / 10;
    unsigned old = __hip_atomic_fetch_add(&cnt32[(24 + sub) * 64], 1u,
                                          __ATOMIC_RELAXED, __HIP_MEMORY_SCOPE_AGENT);
    if ((old % 10u) == 9u)
      __hip_atomic_fetch_add(&cnt32[49 * 64], 1u, __ATOMIC_RELAXED, __HIP_MEMORY_SCOPE_AGENT);
    if (blockIdx.x % 10 == 0) {
      while (__hip_atomic_load(&cnt32[49 * 64], __ATOMIC_RELAXED, __HIP_MEMORY_SCOPE_AGENT) <
             25u * epoch)
        __builtin_amdgcn_s_sleep(1);
      __hip_atomic_store(&cnt32[(50 + sub) * 64], epoch, __ATOMIC_RELAXED,
                         __HIP_MEMORY_SCOPE_AGENT);
    } else {
      while (__hip_atomic_load(&cnt32[(50 + sub) * 64], __ATOMIC_RELAXED,
                               __HIP_MEMORY_SCOPE_AGENT) < epoch)
        __builtin_amdgcn_s_sleep(1);
    }
  }
  __syncthreads();
}

// ---------------- prep kernels ----------------
__global__ void build_tables(const float* __restrict__ info_emb, const float* __restrict__ Wi,
                             const float* __restrict__ bi, const float* __restrict__ q_emb,
                             const float* __restrict__ Wq, const float* __restrict__ bq,
                             float* __restrict__ itab, float* __restrict__ qtab) {
  int idx = blockIdx.x * 256 + threadIdx.x;
  const int N1 = SLEN * 1200;
  if (idx < N1) {
    int r = idx / 1200, c = idx - r * 1200;
    float s = bi[c];
    for (int e = 0; e < ED; ++e) s += info_emb[r * ED + e] * Wi[e * 1200 + c];
    itab[idx] = s;
  } else {
    int i2 = idx - N1;
    int r = i2 / 1200, c = i2 - r * 1200;
    float s = bq[c];
    for (int e = 0; e < ED; ++e) s += q_emb[r * ED + e] * Wq[e * 1200 + c];
    qtab[i2] = s;
  }
}

__global__ void build_mask(const int* __restrict__ info_idx, unsigned long long* __restrict__ mask) {
  int idx = blockIdx.x * 256 + threadIdx.x;  // 128*64
  int b = idx >> 6, j = idx & 63;
  int t = info_idx[idx];
  atomicOr(&mask[(b << 10) + t], 1ull << j);
}

__global__ void k_prod(const __hip_bfloat16* __restrict__ enc_info,
                       const float* __restrict__ enc_q, const int* __restrict__ num_sent,
                       __hip_bfloat16* __restrict__ prod) {
  int idx = blockIdx.x * 256 + threadIdx.x;  // 128*64*416
  int b = idx / (64 * 416);
  int r = idx - b * (64 * 416);
  int j = r / 416, k = r - j * 416;
  float v = 0.f;
  if (k < RD && j <= num_sent[b])
    v = __bfloat162float(enc_info[(b * 64 + j) * RD + k]) * enc_q[b * RD + k];
  prod[idx] = __float2bfloat16(v);
}

// ---------------- fused info+question GRU scan (H=400) ----------------
// blocks 0..79: info (1024 steps, g=bid%8, wgin=bid/8); blocks 80..159: question (64 steps)
__global__ __launch_bounds__(192) void scan_rnn(
    const int* __restrict__ info, const float* __restrict__ itab, const float* __restrict__ Ui,
    const float* __restrict__ bi1, const unsigned long long* __restrict__ mask,
    __hip_bfloat16* __restrict__ encI, const int* __restrict__ question,
    const float* __restrict__ qtab, const float* __restrict__ Uq, const float* __restrict__ bq1,
    const int* __restrict__ qidx, float* __restrict__ encQ, short* __restrict__ hA,
    short* __restrict__ hB, short* __restrict__ hQA, short* __restrict__ hQB,
    unsigned* __restrict__ cnt32) {
  __shared__ short Ut[144 * 424];
  const bool isq = blockIdx.x >= 80;
  const int bid = isq ? blockIdx.x - 80 : blockIdx.x;
  const int g = bid & 7, wgin = bid >> 3;
  const int steps = isq ? 64 : 1024;
  const int* toks = isq ? question : info;
  const float* table = isq ? qtab : itab;
  const float* U = isq ? Uq : Ui;
  const float* b1 = isq ? bq1 : bi1;
  short* bufA = isq ? hQA : hA;
  short* bufB = isq ? hQB : hB;
  unsigned* cnt = cnt32 + (isq ? (8 + g) : g) * 64;
  const int bb = g * 16, dimbase = wgin * 40;

  for (int idx = threadIdx.x; idx < 144 * 416; idx += 192) {
    int cc = idx / 416, k = idx - cc * 416;
    int gate = cc / 48, cl = cc - gate * 48;
    float v = 0.f;
    if (cl < 40 && k < RD) v = U[k * 1200 + gate * RD + dimbase + cl];
    Ut[cc * 424 + k] = f2bf(v);
  }
  __syncthreads();

  const int lane = threadIdx.x & 63, wid = threadIdx.x >> 6;
  const int c = lane & 15, g4 = lane >> 4;
  const int dl = wid * 16 + c;
  const bool valid = dl < 40;
  const int dim = dimbase + dl;
  float b1z = 0, b1r = 0, b1h = 0;
  if (valid) { b1z = b1[dim]; b1r = b1[RD + dim]; b1h = b1[2 * RD + dim]; }
  int rows[4], qm1[4];
  float hreg[4] = {0.f, 0.f, 0.f, 0.f};
#pragma unroll
  for (int i = 0; i < 4; ++i) {
    rows[i] = bb + g4 * 4 + i;
    qm1[i] = isq ? (qidx[rows[i]] - 1) : -1;
  }
  const int bcol = wid * 16 + c, koff = g4 * 8;

  for (int t = 0; t < steps; ++t) {
    const short* cur = (t & 1) ? bufB : bufA;
    short* nxt = (t & 1) ? bufA : bufB;
    const short* arow = cur + (bb + c) * 416 + koff;
    unsigned long long hv[26];
#pragma unroll
    for (int kk = 0; kk < 13; ++kk) {
      hv[2 * kk] = ld_coh64(arow + kk * 32);
      hv[2 * kk + 1] = ld_coh64(arow + kk * 32 + 4);
    }
    float xzv[4], xrv[4], xhv[4];
#pragma unroll
    for (int i = 0; i < 4; ++i) {
      xzv[i] = xrv[i] = xhv[i] = 0.f;
      if (valid) {
        int tok = toks[rows[i] * steps + t];
        const float* trow = table + tok * 1200;
        xzv[i] = trow[dim]; xrv[i] = trow[RD + dim]; xhv[i] = trow[2 * RD + dim];
      }
    }
    f32x4 az = {0,0,0,0}, ar = {0,0,0,0}, ah = {0,0,0,0};
#pragma unroll
    for (int kk = 0; kk < 13; ++kk) {
      U16 u; u.q.lo = hv[2 * kk]; u.q.hi = hv[2 * kk + 1];
      short8 a = u.s;
      az = MFMA(a, *(const short8*)(&Ut[(bcol) * 424 + kk * 32 + koff]), az);
      ar = MFMA(a, *(const short8*)(&Ut[(48 + bcol) * 424 + kk * 32 + koff]), ar);
      ah = MFMA(a, *(const short8*)(&Ut[(96 + bcol) * 424 + kk * 32 + koff]), ah);
    }
#pragma unroll
    for (int i = 0; i < 4; ++i) {
      int m = rows[i];
      float z = sigm(az[i] + xzv[i] + b1z);
      float rr = sigm(ar[i] + xrv[i] + b1r);
      float hh = tanh_f(xhv[i] + rr * (ah[i] + b1h));
      float hn = z * hreg[i] + (1.f - z) * hh;
      hreg[i] = hn;
      unsigned hb = (unsigned short)f2bf(hn);
      unsigned p1 = hb | (((unsigned)__shfl_xor((int)hb, 1, 64)) << 16);
      unsigned long long p2 = (unsigned long long)p1 |
          ((unsigned long long)(unsigned)__shfl_xor((int)p1, 2, 64) << 32);
      if ((c & 3) == 0 && dl + 3 < 40) st_coh64(nxt + m * 416 + dim, p2);
      if (valid) {
        if (!isq) {
          unsigned long long mk = mask[((unsigned)m << 10) + t];
          while (mk) {
            int j = __builtin_ctzll(mk);
            mk &= mk - 1;
            encI[(m * 64 + j) * RD + dim] = __float2bfloat16(hn);
          }
        } else if (t == qm1[i]) {
          encQ[m * RD + dim] = hn;
        }
      }
    }
    grp_barrier(cnt, 10, t + 1);
  }
}

// ---------------- memory GRU (H=300, input prod K=416) ----------------
__global__ __launch_bounds__(128) void scan_mem(
    const __hip_bfloat16* __restrict__ prod, const float* __restrict__ Um,
    const float* __restrict__ Wm, const float* __restrict__ bm, const int* __restrict__ num_sent,
    __hip_bfloat16* __restrict__ hidden, short* __restrict__ hA, short* __restrict__ hB,
    unsigned* __restrict__ cnt32) {
  __shared__ short Ut[96 * 328];
  __shared__ short Wt[96 * 424];
  const int g = blockIdx.x & 7, wgin = blockIdx.x >> 3;
  unsigned* cnt = cnt32 + (16 + g) * 64;
  const int bb = g * 16, dimbase = wgin * 30;

  for (int idx = threadIdx.x; idx < 96 * 320; idx += 128) {
    int cc = idx / 320, k = idx - cc * 320;
    int gate = cc / 32, cl = cc - gate * 32;
    float v = 0.f;
    if (cl < 30 && k < MD) v = Um[k * 900 + gate * MD + dimbase + cl];
    Ut[cc * 328 + k] = f2bf(v);
  }
  for (int idx = threadIdx.x; idx < 96 * 416; idx += 128) {
    int cc = idx / 416, k = idx - cc * 416;
    int gate = cc / 32, cl = cc - gate * 32;
    float v = 0.f;
    if (cl < 30 && k < RD) v = Wm[k * 900 + gate * MD + dimbase + cl];
    Wt[cc * 424 + k] = f2bf(v);
  }
  __syncthreads();

  const int lane = threadIdx.x & 63, wid = threadIdx.x >> 6;
  const int c = lane & 15, g4 = lane >> 4;
  const int dl = wid * 16 + c;
  const bool valid = dl < 30;
  const int dim = dimbase + dl;
  float cbz = 0, cbr = 0, b0h = 0, b1h = 0;
  if (valid) {
    cbz = bm[dim] + bm[900 + dim];
    cbr = bm[MD + dim] + bm[900 + MD + dim];
    b0h = bm[2 * MD + dim];
    b1h = bm[900 + 2 * MD + dim];
  }
  int rows[4], ns[4];
  float hreg[4] = {0.f, 0.f, 0.f, 0.f};
#pragma unroll
  for (int i = 0; i < 4; ++i) {
    rows[i] = bb + g4 * 4 + i;
    ns[i] = num_sent[rows[i]];
  }
  const int bcol = wid * 16 + c, koff = g4 * 8;

  for (int t = 0; t < 64; ++t) {
    const short* cur = (t & 1) ? hB : hA;
    short* nxt = (t & 1) ? hA : hB;
    const short* hrow = cur + (bb + c) * 320 + koff;
    unsigned long long hv[20];
#pragma unroll
    for (int kk = 0; kk < 10; ++kk) {
      hv[2 * kk] = ld_coh64(hrow + kk * 32);
      hv[2 * kk + 1] = ld_coh64(hrow + kk * 32 + 4);
    }
    f32x4 az = {0,0,0,0}, ar = {0,0,0,0}, arh = {0,0,0,0}, axh = {0,0,0,0};
#pragma unroll
    for (int kk = 0; kk < 10; ++kk) {
      U16 u; u.q.lo = hv[2 * kk]; u.q.hi = hv[2 * kk + 1];
      short8 a = u.s;
      az = MFMA(a, *(const short8*)(&Ut[(bcol) * 328 + kk * 32 + koff]), az);
      ar = MFMA(a, *(const short8*)(&Ut[(32 + bcol) * 328 + kk * 32 + koff]), ar);
      arh = MFMA(a, *(const short8*)(&Ut[(64 + bcol) * 328 + kk * 32 + koff]), arh);
    }
    const short* xrow = (const short*)prod + (bb + c) * (64 * 416) + t * 416 + koff;
#pragma unroll
    for (int kx = 0; kx < 13; ++kx) {
      short8 a = *(const short8*)(xrow + kx * 32);
      az = MFMA(a, *(const short8*)(&Wt[(bcol) * 424 + kx * 32 + koff]), az);
      ar = MFMA(a, *(const short8*)(&Wt[(32 + bcol) * 424 + kx * 32 + koff]), ar);
      axh = MFMA(a, *(const short8*)(&Wt[(64 + bcol) * 424 + kx * 32 + koff]), axh);
    }
#pragma unroll
    for (int i = 0; i < 4; ++i) {
      int m = rows[i];
      float z = sigm(az[i] + cbz);
      float rr = sigm(ar[i] + cbr);
      float hh = tanh_f(axh[i] + b0h + rr * (arh[i] + b1h));
      float hn = z * hreg[i] + (1.f - z) * hh;
      hreg[i] = hn;
      unsigned hb = (unsigned short)f2bf(hn);
      unsigned p1 = hb | (((unsigned)__shfl_xor((int)hb, 1, 64)) << 16);
      unsigned long long p2 = (unsigned long long)p1 |
          ((unsigned long long)(unsigned)__shfl_xor((int)p1, 2, 64) << 32);
      if ((c & 3) == 0) {
        if (dl + 3 < 30) st_coh64(nxt + m * 320 + dim, p2);
        else if (dl < 30) st_coh32(nxt + m * 320 + dim, p1);  // dims 28,29
      }
      if (valid)
        hidden[(m * 64 + t) * 320 + dim] =
            (t <= ns[i]) ? __float2bfloat16(hn) : __float2bfloat16(0.f);
    }
    grp_barrier(cnt, 10, t + 1);
  }
}

// ---------------- answer GRU (H=2000, softmax candidate) ----------------
// 250 WGs x 512 thr; WG owns 8 cols; 2 relaxed barriers/step.
__global__ __launch_bounds__(512) void scan_ans(
    const __hip_bfloat16* __restrict__ hidden, const float* __restrict__ Ua,
    const float* __restrict__ Wa, const float* __restrict__ ba, float* __restrict__ out,
    short* __restrict__ hAns, float* __restrict__ partials, unsigned* __restrict__ cnt32) {
  __shared__ short Ut[32 * 2056];
  __shared__ short Wt[32 * 328];
  const int w = blockIdx.x;
  const int wbase = w * 8;

  for (int idx = threadIdx.x; idx < 32 * 2048; idx += 512) {
    int cc = idx / 2048, k = idx - cc * 2048;
    int sel = cc >> 3, cl = cc & 7;
    float v = 0.f;
    if (sel < 3 && k < VD) v = Ua[k * 6000 + sel * VD + wbase + cl];
    Ut[cc * 2056 + k] = f2bf(v);
  }
  for (int idx = threadIdx.x; idx < 32 * 320; idx += 512) {
    int cc = idx / 320, k = idx - cc * 320;
    int sel = cc >> 3, cl = cc & 7;
    float v = 0.f;
    if (sel < 3 && k < MD) v = Wa[k * 6000 + sel * VD + wbase + cl];
    Wt[cc * 328 + k] = f2bf(v);
  }
  __syncthreads();
  unsigned ep = 1;

  const int lane = threadIdx.x & 63, wid = threadIdx.x >> 6;
  const int c = lane & 15, g4 = lane >> 4;
  const bool zlane = c < 8;
  const int dim = wbase + (c & 7);
  float cbz = 0, cbr = 0, b0h = 0, b1h = 0;
  if (zlane) {
    cbz = ba[dim] + ba[6000 + dim];
    cbr = ba[VD + dim] + ba[6000 + VD + dim];
    b0h = ba[2 * VD + dim];
    b1h = ba[6000 + 2 * VD + dim];
  }
  int rows[4];
  float hreg[4] = {0.f, 0.f, 0.f, 0.f};
#pragma unroll
  for (int i = 0; i < 4; ++i) rows[i] = wid * 16 + g4 * 4 + i;
  const int koff = g4 * 8;

  for (int t = 0; t < 64; ++t) {
    f32x4 azr = {0,0,0,0}, arh = {0,0,0,0}, axh = {0,0,0,0};
    const short* xrow = (const short*)hidden + (wid * 16 + c) * (64 * 320) + t * 320 + koff;
#pragma unroll
    for (int kx = 0; kx < 10; ++kx) {
      short8 a = *(const short8*)(xrow + kx * 32);
      azr = MFMA(a, *(const short8*)(&Wt[c * 328 + kx * 32 + koff]), azr);
      axh = MFMA(a, *(const short8*)(&Wt[(16 + c) * 328 + kx * 32 + koff]), axh);
    }
    const short* hrow = hAns + (wid * 16 + c) * 2048 + koff;
#pragma unroll 2
    for (int kc = 0; kc < 8; ++kc) {
      unsigned long long hv[16];
#pragma unroll
      for (int kk = 0; kk < 8; ++kk) {
        hv[2 * kk] = ld_coh64(hrow + (kc * 8 + kk) * 32);
        hv[2 * kk + 1] = ld_coh64(hrow + (kc * 8 + kk) * 32 + 4);
      }
#pragma unroll
      for (int kk = 0; kk < 8; ++kk) {
        U16 u; u.q.lo = hv[2 * kk]; u.q.hi = hv[2 * kk + 1];
        short8 a = u.s;
        int kkk = kc * 8 + kk;
        azr = MFMA(a, *(const short8*)(&Ut[c * 2056 + kkk * 32 + koff]), azr);
        arh = MFMA(a, *(const short8*)(&Ut[(16 + c) * 2056 + kkk * 32 + koff]), arh);
      }
    }
    float z4[4], ee[4], er[4];
#pragma unroll
    for (int i = 0; i < 4; ++i) {
      float rzv = __shfl_xor(azr[i], 8, 64);  // r-gate partial for z-lanes
      float z = sigm(azr[i] + cbz);
      float rr = sigm(rzv + cbr);
      float lg = (axh[i] + b0h) + rr * (arh[i] + b1h);
      float e = zlane ? __expf(lg) : 0.f;
      z4[i] = z; ee[i] = e; er[i] = e;
    }
#pragma unroll
    for (int d = 1; d <= 4; d <<= 1)
#pragma unroll
      for (int i = 0; i < 4; ++i) er[i] += __shfl_xor(er[i], d, 64);
    if (c == 0) {
#pragma unroll
      for (int i = 0; i < 4; ++i)
        __hip_atomic_store(&partials[rows[i] * 256 + w], er[i], __ATOMIC_RELAXED,
                           __HIP_MEMORY_SCOPE_AGENT);
    }
    ans_barrier(cnt32, ep++);  // A: partials ready
    float T4[4];
#pragma unroll
    for (int i = 0; i < 4; ++i) {
      float s = 0.f;
#pragma unroll
      for (int k = 0; k < 8; ++k) {
        unsigned long long pv = ld_coh64(&partials[rows[i] * 256 + c * 16 + k * 2]);
        float2 f = __builtin_bit_cast(float2, pv);
        s += f.x + f.y;
      }
#pragma unroll
      for (int d = 1; d <= 8; d <<= 1) s += __shfl_xor(s, d, 16);
      T4[i] = s;
    }
#pragma unroll
    for (int i = 0; i < 4; ++i) {
      float hh = ee[i] / T4[i];
      float hn = z4[i] * hreg[i] + (1.f - z4[i]) * hh;
      hreg[i] = hn;
      unsigned hb = (unsigned short)f2bf(hn);
      unsigned p1 = hb | (((unsigned)__shfl_xor((int)hb, 1, 64)) << 16);
      unsigned long long p2 = (unsigned long long)p1 |
          ((unsigned long long)(unsigned)__shfl_xor((int)p1, 2, 64) << 32);
      if (zlane && (c & 3) == 0) st_coh64(hAns + rows[i] * 2048 + wbase + c, p2);
      if (zlane) out[(rows[i] * 64 + t) * VD + dim] = hn;
    }
    ans_barrier(cnt32, ep++);  // B: h ready for next step
  }
}

// ---------------- launch ----------------
extern "C" void kernel_launch(void* const* d_in, const int* in_sizes, int n_in, void* d_out,
                              int out_size, void* d_ws, size_t ws_size, hipStream_t stream) {
  (void)in_sizes; (void)n_in; (void)out_size;
  if (ws_size < (size_t)WS_NEED) return;

  const int* info = (const int*)d_in[0];
  const int* info_idx = (const int*)d_in[1];
  const int* num_sent = (const int*)d_in[2];
  const int* question = (const int*)d_in[3];
  const int* qidx = (const int*)d_in[4];
  const float* info_emb = (const float*)d_in[5];
  const float* Wi = (const float*)d_in[6];
  const float* Ui = (const float*)d_in[7];
  const float* bi = (const float*)d_in[8];
  const float* q_emb = (const float*)d_in[9];
  const float* Wq = (const float*)d_in[10];
  const float* Uq = (const float*)d_in[11];
  const float* bq = (const float*)d_in[12];
  const float* Wm = (const float*)d_in[13];
  const float* Um = (const float*)d_in[14];
  const float* bm = (const float*)d_in[15];
  const float* Wa = (const float*)d_in[16];
  const float* Ua = (const float*)d_in[17];
  const float* ba = (const float*)d_in[18];

  char* ws = (char*)d_ws;
  unsigned* cnt32 = (unsigned*)(ws + OFF_CNT);
  float* partials = (float*)(ws + OFF_PART);
  unsigned long long* mask = (unsigned long long*)(ws + OFF_MASK);
  float* itab = (float*)(ws + OFF_ITAB);
  float* qtab = (float*)(ws + OFF_QTAB);
  __hip_bfloat16* enc_info = (__hip_bfloat16*)(ws + OFF_EINFO);
  float* enc_q = (float*)(ws + OFF_EQ);
  __hip_bfloat16* prod = (__hip_bfloat16*)(ws + OFF_PROD);
  __hip_bfloat16* hidden = (__hip_bfloat16*)(ws + OFF_HIDDEN);
  short* hA = (short*)(ws + OFF_HA);
  short* hB = (short*)(ws + OFF_HB);
  short* hQA = (short*)(ws + OFF_HQA);
  short* hQB = (short*)(ws + OFF_HQB);
  short* hMA = (short*)(ws + OFF_HMA);
  short* hMB = (short*)(ws + OFF_HMB);
  short* hAns = (short*)(ws + OFF_HANS);

  // zero: counters+partials+mask; hidden (pad cols); all h exchange buffers
  hipMemsetAsync(ws, 0, OFF_ITAB, stream);
  hipMemsetAsync(ws + OFF_HIDDEN, 0, 128 * 64 * 320 * 2, stream);
  hipMemsetAsync(ws + OFF_HA, 0, WS_NEED - OFF_HA, stream);

  build_tables<<<5100, 256, 0, stream>>>(info_emb, Wi, bi, q_emb, Wq, bq, itab, qtab);
  build_mask<<<32, 256, 0, stream>>>(info_idx, mask);
  scan_rnn<<<160, 192, 0, stream>>>(info, itab, Ui, bi + 1200, mask, enc_info, question, qtab,
                                    Uq, bq + 1200, qidx, enc_q, hA, hB, hQA, hQB, cnt32);
  k_prod<<<13312, 256, 0, stream>>>(enc_info, enc_q, num_sent, prod);
  scan_mem<<<80, 128, 0, stream>>>(prod, Um, Wm, bm, num_sent, hidden, hMA, hMB, cnt32);
  scan_ans<<<250, 512, 0, stream>>>(hidden, Ua, Wa, ba, (float*)d_out, hAns, partials, cnt32);
}

// Round 5
// 8002.769 us; speedup vs baseline: 2.2031x; 1.2755x over previous
//
#include <hip/hip_runtime.h>
#include <hip/hip_bf16.h>

// ---------------- problem dims ----------------
#define NB 128
#define SLEN 1024
#define NSENT 64
#define QLEN 64
#define ED 50
#define RD 400
#define MD 300
#define VD 2000

typedef short short8 __attribute__((ext_vector_type(8)));
typedef float f32x4 __attribute__((ext_vector_type(4)));
typedef int i32x4 __attribute__((ext_vector_type(4)));

__device__ __forceinline__ f32x4 MFMA(short8 a, short8 b, f32x4 c) {
  return __builtin_amdgcn_mfma_f32_16x16x32_bf16(a, b, c, 0, 0, 0);
}
__device__ __forceinline__ float sigm(float x) { return 1.f / (1.f + __expf(-x)); }
__device__ __forceinline__ float tanh_f(float x) {
  x = fminf(fmaxf(x, -15.f), 15.f);
  float e = __expf(2.f * x);
  return (e - 1.f) / (e + 1.f);
}
__device__ __forceinline__ short f2bf(float v) {
  __hip_bfloat16 h = __float2bfloat16(v);
  return *reinterpret_cast<short*>(&h);
}

// ---- coherent (device-scope, L1/L2-bypass) access via inline asm: PIPELINED ----
__device__ __forceinline__ short8 ldg16(const void* p) {
  i32x4 r;
  asm volatile("global_load_dwordx4 %0, %1, off sc0 sc1" : "=v"(r) : "v"(p));
  return __builtin_bit_cast(short8, r);
}
__device__ __forceinline__ f32x4 ldg16f(const void* p) {
  f32x4 r;
  asm volatile("global_load_dwordx4 %0, %1, off sc0 sc1" : "=v"(r) : "v"(p));
  return r;
}
__device__ __forceinline__ void stg8(void* p, unsigned long long v) {
  asm volatile("global_store_dwordx2 %0, %1, off sc0 sc1" ::"v"(p), "v"(v));
}
__device__ __forceinline__ void stg4(void* p, unsigned v) {
  asm volatile("global_store_dword %0, %1, off sc0 sc1" ::"v"(p), "v"(v));
}
#define VMCNT0()                                     \
  {                                                  \
    asm volatile("s_waitcnt vmcnt(0)" ::: "memory"); \
    __builtin_amdgcn_sched_barrier(0);               \
  }

// ---------------- workspace layout (bytes) ----------------
// stamp lines: u32 slot base i*64 (256B per region)
//   info groups g: slot g (stamps [0..9]) ; q: 8+g ; mem: 16+g
//   ans subs s(0..24): 24+s (stamps [0..9]) ; ans agg: slot 49 (u32 [0..24])
#define OFF_CNT     0u          // 20480
#define OFF_PART    20480u      // [128][256] f32 = 131072
#define OFF_MASK    151552u     // [128][1024] u64 = 1048576
#define OFF_ITAB    1200128u    // [1024][1200] f32 = 4915200
#define OFF_QTAB    6115328u    // [64][1200] f32 = 307200
#define OFF_EINFO   6422528u    // [128][64][400] bf16 = 6553600
#define OFF_EQ      12976128u   // [128][400] f32 = 204800
#define OFF_PROD    13180928u   // [128][64][416] bf16 = 6815744
#define OFF_HIDDEN  19996672u   // [128][64][320] bf16 = 5242880
#define OFF_HA      25239552u   // [128][416] bf16 = 106496
#define OFF_HB      25346048u
#define OFF_HQA     25452544u
#define OFF_HQB     25559040u
#define OFF_HMA     25665536u   // [128][320] bf16 = 81920
#define OFF_HMB     25747456u
#define OFF_HANS    25829376u   // [128][2048] bf16 = 524288
#define WS_NEED     26353664u

// ---------------- stamp barrier primitives ----------------
// poll a line of n u32 stamps until all >= v (wave 0 only; one coalesced load/iter)
__device__ __forceinline__ void poll_line(const unsigned* base, int n, unsigned v, int lane) {
  bool mine = lane < n;
  const unsigned* p = base + (mine ? lane : 0);
  for (;;) {
    unsigned s;
    asm volatile("global_load_dword %0, %1, off sc0 sc1\n\ts_waitcnt vmcnt(0)"
                 : "=v"(s) : "v"(p) : "memory");
    if (__all(!mine || s >= v)) break;
    __builtin_amdgcn_s_sleep(1);
  }
}
// wait until all n stamps of `stamps` reach v; then block-sync.
__device__ __forceinline__ void stamp_wait(const unsigned* stamps, int n, unsigned v, int wid,
                                           int lane) {
  if (v && wid == 0) poll_line(stamps, n, v, lane);
  __syncthreads();
}

// 250-WG hierarchical: post own stamp; sub-leaders aggregate to agg line; all poll agg.
__device__ __forceinline__ void ans_post(unsigned* cnt32, unsigned v, int w) {
  if (threadIdx.x == 0) stg4(&cnt32[(24 + w / 10) * 64 + (w % 10)], v);
}
__device__ __forceinline__ void ans_wait(unsigned* cnt32, unsigned v, int w, int wid, int lane) {
  if (v) {
    if (wid == 0) {
      if (w % 10 == 0) {
        poll_line(&cnt32[(24 + w / 10) * 64], 10, v, lane);
        if (lane == 0) stg4(&cnt32[49 * 64 + w / 10], v);
      }
      poll_line(&cnt32[49 * 64], 25, v, lane);
    }
  }
  __syncthreads();
}

// ---------------- prep kernels ----------------
__global__ void build_tables(const float* __restrict__ info_emb, const float* __restrict__ Wi,
                             const float* __restrict__ bi, const float* __restrict__ q_emb,
                             const float* __restrict__ Wq, const float* __restrict__ bq,
                             float* __restrict__ itab, float* __restrict__ qtab) {
  int idx = blockIdx.x * 256 + threadIdx.x;
  const int N1 = SLEN * 1200;
  if (idx < N1) {
    int r = idx / 1200, c = idx - r * 1200;
    float s = bi[c];
    for (int e = 0; e < ED; ++e) s += info_emb[r * ED + e] * Wi[e * 1200 + c];
    itab[idx] = s;
  } else {
    int i2 = idx - N1;
    int r = i2 / 1200, c = i2 - r * 1200;
    float s = bq[c];
    for (int e = 0; e < ED; ++e) s += q_emb[r * ED + e] * Wq[e * 1200 + c];
    qtab[i2] = s;
  }
}

__global__ void build_mask(const int* __restrict__ info_idx, unsigned long long* __restrict__ mask) {
  int idx = blockIdx.x * 256 + threadIdx.x;  // 128*64
  int b = idx >> 6, j = idx & 63;
  int t = info_idx[idx];
  atomicOr(&mask[(b << 10) + t], 1ull << j);
}

__global__ void k_prod(const __hip_bfloat16* __restrict__ enc_info,
                       const float* __restrict__ enc_q, const int* __restrict__ num_sent,
                       __hip_bfloat16* __restrict__ prod) {
  int idx = blockIdx.x * 256 + threadIdx.x;  // 128*64*416
  int b = idx / (64 * 416);
  int r = idx - b * (64 * 416);
  int j = r / 416, k = r - j * 416;
  float v = 0.f;
  if (k < RD && j <= num_sent[b])
    v = __bfloat162float(enc_info[(b * 64 + j) * RD + k]) * enc_q[b * RD + k];
  prod[idx] = __float2bfloat16(v);
}

// ---------------- fused info+question GRU scan (H=400) ----------------
// blocks 0..79: info (1024 steps, g=bid%8, wgin=bid/8); blocks 80..159: question (64 steps)
__global__ __launch_bounds__(192) void scan_rnn(
    const int* __restrict__ info, const float* __restrict__ itab, const float* __restrict__ Ui,
    const float* __restrict__ bi1, const unsigned long long* __restrict__ mask,
    __hip_bfloat16* __restrict__ encI, const int* __restrict__ question,
    const float* __restrict__ qtab, const float* __restrict__ Uq, const float* __restrict__ bq1,
    const int* __restrict__ qidx, float* __restrict__ encQ, short* __restrict__ hA,
    short* __restrict__ hB, short* __restrict__ hQA, short* __restrict__ hQB,
    unsigned* __restrict__ cnt32) {
  __shared__ short Ut[144 * 424];
  const bool isq = blockIdx.x >= 80;
  const int bid = isq ? blockIdx.x - 80 : blockIdx.x;
  const int g = bid & 7, wgin = bid >> 3;
  const int steps = isq ? 64 : 1024;
  const int* toks = isq ? question : info;
  const float* table = isq ? qtab : itab;
  const float* U = isq ? Uq : Ui;
  const float* b1 = isq ? bq1 : bi1;
  short* bufA = isq ? hQA : hA;
  short* bufB = isq ? hQB : hB;
  unsigned* stamps = cnt32 + (isq ? (8 + g) : g) * 64;
  const int bb = g * 16, dimbase = wgin * 40;

  for (int idx = threadIdx.x; idx < 144 * 416; idx += 192) {
    int cc = idx / 416, k = idx - cc * 416;
    int gate = cc / 48, cl = cc - gate * 48;
    float v = 0.f;
    if (cl < 40 && k < RD) v = U[k * 1200 + gate * RD + dimbase + cl];
    Ut[cc * 424 + k] = f2bf(v);
  }
  __syncthreads();

  const int lane = threadIdx.x & 63, wid = threadIdx.x >> 6;
  const int c = lane & 15, g4 = lane >> 4;
  const int dl = wid * 16 + c;
  const bool valid = dl < 40;
  const int dim = dimbase + dl;
  float b1z = 0, b1r = 0, b1h = 0;
  if (valid) { b1z = b1[dim]; b1r = b1[RD + dim]; b1h = b1[2 * RD + dim]; }
  int rows[4], qm1[4];
  float hreg[4] = {0.f, 0.f, 0.f, 0.f};
#pragma unroll
  for (int i = 0; i < 4; ++i) {
    rows[i] = bb + g4 * 4 + i;
    qm1[i] = isq ? (qidx[rows[i]] - 1) : -1;
  }
  const int bcol = wid * 16 + c, koff = g4 * 8;

  for (int t = 0; t < steps; ++t) {
    // gather x(t) early (plain cached loads) — overlaps the stamp poll
    float xzv[4], xrv[4], xhv[4];
#pragma unroll
    for (int i = 0; i < 4; ++i) {
      xzv[i] = xrv[i] = xhv[i] = 0.f;
      if (valid) {
        int tok = toks[rows[i] * steps + t];
        const float* trow = table + tok * 1200;
        xzv[i] = trow[dim]; xrv[i] = trow[RD + dim]; xhv[i] = trow[2 * RD + dim];
      }
    }
    stamp_wait(stamps, 10, (unsigned)t, wid, lane);  // h(t) visible

    const short* cur = (t & 1) ? bufB : bufA;
    short* nxt = (t & 1) ? bufA : bufB;
    const short* arow = cur + (bb + c) * 416 + koff;
    short8 hv[13];
#pragma unroll
    for (int kk = 0; kk < 13; ++kk) hv[kk] = ldg16(arow + kk * 32);
    VMCNT0();
    f32x4 az = {0, 0, 0, 0}, ar = {0, 0, 0, 0}, ah = {0, 0, 0, 0};
#pragma unroll
    for (int kk = 0; kk < 13; ++kk) {
      az = MFMA(hv[kk], *(const short8*)(&Ut[(bcol)*424 + kk * 32 + koff]), az);
      ar = MFMA(hv[kk], *(const short8*)(&Ut[(48 + bcol) * 424 + kk * 32 + koff]), ar);
      ah = MFMA(hv[kk], *(const short8*)(&Ut[(96 + bcol) * 424 + kk * 32 + koff]), ah);
    }
#pragma unroll
    for (int i = 0; i < 4; ++i) {
      int m = rows[i];
      float z = sigm(az[i] + xzv[i] + b1z);
      float rr = sigm(ar[i] + xrv[i] + b1r);
      float hh = tanh_f(xhv[i] + rr * (ah[i] + b1h));
      float hn = z * hreg[i] + (1.f - z) * hh;
      hreg[i] = hn;
      unsigned hb = (unsigned short)f2bf(hn);
      unsigned p1 = hb | (((unsigned)__shfl_xor((int)hb, 1, 64)) << 16);
      unsigned long long p2 = (unsigned long long)p1 |
          ((unsigned long long)(unsigned)__shfl_xor((int)p1, 2, 64) << 32);
      if ((c & 3) == 0 && dl + 3 < 40) stg8(nxt + m * 416 + dim, p2);
      if (valid) {
        if (!isq) {
          unsigned long long mk = mask[((unsigned)m << 10) + t];
          while (mk) {
            int j = __builtin_ctzll(mk);
            mk &= mk - 1;
            encI[(m * 64 + j) * RD + dim] = __float2bfloat16(hn);
          }
        } else if (t == qm1[i]) {
          encQ[m * RD + dim] = hn;
        }
      }
    }
    VMCNT0();
    __syncthreads();
    if (threadIdx.x == 0) stg4(stamps + wgin, (unsigned)(t + 1));
  }
}

// ---------------- memory GRU (H=300, input prod K=416) ----------------
__global__ __launch_bounds__(128) void scan_mem(
    const __hip_bfloat16* __restrict__ prod, const float* __restrict__ Um,
    const float* __restrict__ Wm, const float* __restrict__ bm, const int* __restrict__ num_sent,
    __hip_bfloat16* __restrict__ hidden, short* __restrict__ hA, short* __restrict__ hB,
    unsigned* __restrict__ cnt32) {
  __shared__ short Ut[96 * 328];
  __shared__ short Wt[96 * 424];
  const int g = blockIdx.x & 7, wgin = blockIdx.x >> 3;
  unsigned* stamps = cnt32 + (16 + g) * 64;
  const int bb = g * 16, dimbase = wgin * 30;

  for (int idx = threadIdx.x; idx < 96 * 320; idx += 128) {
    int cc = idx / 320, k = idx - cc * 320;
    int gate = cc / 32, cl = cc - gate * 32;
    float v = 0.f;
    if (cl < 30 && k < MD) v = Um[k * 900 + gate * MD + dimbase + cl];
    Ut[cc * 328 + k] = f2bf(v);
  }
  for (int idx = threadIdx.x; idx < 96 * 416; idx += 128) {
    int cc = idx / 416, k = idx - cc * 416;
    int gate = cc / 32, cl = cc - gate * 32;
    float v = 0.f;
    if (cl < 30 && k < RD) v = Wm[k * 900 + gate * MD + dimbase + cl];
    Wt[cc * 424 + k] = f2bf(v);
  }
  __syncthreads();

  const int lane = threadIdx.x & 63, wid = threadIdx.x >> 6;
  const int c = lane & 15, g4 = lane >> 4;
  const int dl = wid * 16 + c;
  const bool valid = dl < 30;
  const int dim = dimbase + dl;
  float cbz = 0, cbr = 0, b0h = 0, b1h = 0;
  if (valid) {
    cbz = bm[dim] + bm[900 + dim];
    cbr = bm[MD + dim] + bm[900 + MD + dim];
    b0h = bm[2 * MD + dim];
    b1h = bm[900 + 2 * MD + dim];
  }
  int rows[4], ns[4];
  float hreg[4] = {0.f, 0.f, 0.f, 0.f};
#pragma unroll
  for (int i = 0; i < 4; ++i) {
    rows[i] = bb + g4 * 4 + i;
    ns[i] = num_sent[rows[i]];
  }
  const int bcol = wid * 16 + c, koff = g4 * 8;

  for (int t = 0; t < 64; ++t) {
    // x-part (plain cached loads) BEFORE the wait — overlaps barrier latency
    f32x4 az = {0, 0, 0, 0}, ar = {0, 0, 0, 0}, arh = {0, 0, 0, 0}, axh = {0, 0, 0, 0};
    const short* xrow = (const short*)prod + (bb + c) * (64 * 416) + t * 416 + koff;
#pragma unroll
    for (int kx = 0; kx < 13; ++kx) {
      short8 a = *(const short8*)(xrow + kx * 32);
      az = MFMA(a, *(const short8*)(&Wt[(bcol)*424 + kx * 32 + koff]), az);
      ar = MFMA(a, *(const short8*)(&Wt[(32 + bcol) * 424 + kx * 32 + koff]), ar);
      axh = MFMA(a, *(const short8*)(&Wt[(64 + bcol) * 424 + kx * 32 + koff]), axh);
    }
    stamp_wait(stamps, 10, (unsigned)t, wid, lane);  // h(t) visible

    const short* cur = (t & 1) ? hB : hA;
    short* nxt = (t & 1) ? hA : hB;
    const short* hrow = cur + (bb + c) * 320 + koff;
    short8 hv[10];
#pragma unroll
    for (int kk = 0; kk < 10; ++kk) hv[kk] = ldg16(hrow + kk * 32);
    VMCNT0();
#pragma unroll
    for (int kk = 0; kk < 10; ++kk) {
      az = MFMA(hv[kk], *(const short8*)(&Ut[(bcol)*328 + kk * 32 + koff]), az);
      ar = MFMA(hv[kk], *(const short8*)(&Ut[(32 + bcol) * 328 + kk * 32 + koff]), ar);
      arh = MFMA(hv[kk], *(const short8*)(&Ut[(64 + bcol) * 328 + kk * 32 + koff]), arh);
    }
#pragma unroll
    for (int i = 0; i < 4; ++i) {
      int m = rows[i];
      float z = sigm(az[i] + cbz);
      float rr = sigm(ar[i] + cbr);
      float hh = tanh_f(axh[i] + b0h + rr * (arh[i] + b1h));
      float hn = z * hreg[i] + (1.f - z) * hh;
      hreg[i] = hn;
      unsigned hb = (unsigned short)f2bf(hn);
      unsigned p1 = hb | (((unsigned)__shfl_xor((int)hb, 1, 64)) << 16);
      unsigned long long p2 = (unsigned long long)p1 |
          ((unsigned long long)(unsigned)__shfl_xor((int)p1, 2, 64) << 32);
      if ((c & 3) == 0) {
        if (dl + 3 < 30) stg8(nxt + m * 320 + dim, p2);
        else if (dl < 30) stg4(nxt + m * 320 + dim, p1);  // dims 28,29
      }
      if (valid)
        hidden[(m * 64 + t) * 320 + dim] =
            (t <= ns[i]) ? __float2bfloat16(hn) : __float2bfloat16(0.f);
    }
    VMCNT0();
    __syncthreads();
    if (threadIdx.x == 0) stg4(stamps + wgin, (unsigned)(t + 1));
  }
}

// ---------------- answer GRU (H=2000, softmax candidate) ----------------
// 250 WGs x 512 thr; WG owns 8 cols; 2 stamp-phases/step.
__global__ __launch_bounds__(512) void scan_ans(
    const __hip_bfloat16* __restrict__ hidden, const float* __restrict__ Ua,
    const float* __restrict__ Wa, const float* __restrict__ ba, float* __restrict__ out,
    short* __restrict__ hAns, float* __restrict__ partials, unsigned* __restrict__ cnt32) {
  __shared__ short Ut[32 * 2056];
  __shared__ short Wt[32 * 328];
  const int w = blockIdx.x;
  const int wbase = w * 8;

  for (int idx = threadIdx.x; idx < 32 * 2048; idx += 512) {
    int cc = idx / 2048, k = idx - cc * 2048;
    int sel = cc >> 3, cl = cc & 7;
    float v = 0.f;
    if (sel < 3 && k < VD) v = Ua[k * 6000 + sel * VD + wbase + cl];
    Ut[cc * 2056 + k] = f2bf(v);
  }
  for (int idx = threadIdx.x; idx < 32 * 320; idx += 512) {
    int cc = idx / 320, k = idx - cc * 320;
    int sel = cc >> 3, cl = cc & 7;
    float v = 0.f;
    if (sel < 3 && k < MD) v = Wa[k * 6000 + sel * VD + wbase + cl];
    Wt[cc * 328 + k] = f2bf(v);
  }
  __syncthreads();

  const int lane = threadIdx.x & 63, wid = threadIdx.x >> 6;
  const int c = lane & 15, g4 = lane >> 4;
  const bool zlane = c < 8;
  const int dim = wbase + (c & 7);
  float cbz = 0, cbr = 0, b0h = 0, b1h = 0;
  if (zlane) {
    cbz = ba[dim] + ba[6000 + dim];
    cbr = ba[VD + dim] + ba[6000 + VD + dim];
    b0h = ba[2 * VD + dim];
    b1h = ba[6000 + 2 * VD + dim];
  }
  int rows[4];
  float hreg[4] = {0.f, 0.f, 0.f, 0.f};
#pragma unroll
  for (int i = 0; i < 4; ++i) rows[i] = wid * 16 + g4 * 4 + i;
  const int koff = g4 * 8;

  for (int t = 0; t < 64; ++t) {
    f32x4 azr = {0, 0, 0, 0}, arh = {0, 0, 0, 0}, axh = {0, 0, 0, 0};
    // x-part before the wait (plain cached loads of `hidden`)
    const short* xrow = (const short*)hidden + (wid * 16 + c) * (64 * 320) + t * 320 + koff;
#pragma unroll
    for (int kx = 0; kx < 10; ++kx) {
      short8 a = *(const short8*)(xrow + kx * 32);
      azr = MFMA(a, *(const short8*)(&Wt[c * 328 + kx * 32 + koff]), azr);
      axh = MFMA(a, *(const short8*)(&Wt[(16 + c) * 328 + kx * 32 + koff]), axh);
    }
    ans_wait(cnt32, 2u * t, w, wid, lane);  // hAns(t) visible (t=0 trivial)

    const short* hrow = hAns + (wid * 16 + c) * 2048 + koff;
    short8 hv[16];
#pragma unroll 1
    for (int b = 0; b < 4; ++b) {
#pragma unroll
      for (int kk = 0; kk < 16; ++kk) hv[kk] = ldg16(hrow + (b * 16 + kk) * 32);
      VMCNT0();
#pragma unroll
      for (int kk = 0; kk < 16; ++kk) {
        azr = MFMA(hv[kk], *(const short8*)(&Ut[c * 2056 + (b * 16 + kk) * 32 + koff]), azr);
        arh = MFMA(hv[kk], *(const short8*)(&Ut[(16 + c) * 2056 + (b * 16 + kk) * 32 + koff]),
                   arh);
      }
    }
    float z4[4], ee[4], er[4];
#pragma unroll
    for (int i = 0; i < 4; ++i) {
      float rzv = __shfl_xor(azr[i], 8, 64);  // r-gate partial for z-lanes
      float z = sigm(azr[i] + cbz);
      float rr = sigm(rzv + cbr);
      float lg = (axh[i] + b0h) + rr * (arh[i] + b1h);
      float e = zlane ? __expf(lg) : 0.f;
      z4[i] = z; ee[i] = e; er[i] = e;
    }
#pragma unroll
    for (int d = 1; d <= 4; d <<= 1)
#pragma unroll
      for (int i = 0; i < 4; ++i) er[i] += __shfl_xor(er[i], d, 64);
    if (c == 0) {
#pragma unroll
      for (int i = 0; i < 4; ++i)
        stg4(&partials[rows[i] * 256 + w], __builtin_bit_cast(unsigned, er[i]));
    }
    VMCNT0();
    __syncthreads();
    ans_post(cnt32, 2u * t + 1, w);
    ans_wait(cnt32, 2u * t + 1, w, wid, lane);  // partials visible

    f32x4 sv[16];
#pragma unroll
    for (int i = 0; i < 4; ++i)
#pragma unroll
      for (int k = 0; k < 4; ++k)
        sv[i * 4 + k] = ldg16f(partials + rows[i] * 256 + c * 16 + k * 4);
    VMCNT0();
    float T4[4];
#pragma unroll
    for (int i = 0; i < 4; ++i) {
      float s = 0.f;
#pragma unroll
      for (int k = 0; k < 4; ++k) {
        f32x4 v = sv[i * 4 + k];
        s += v[0] + v[1] + v[2] + v[3];
      }
#pragma unroll
      for (int d = 1; d <= 8; d <<= 1) s += __shfl_xor(s, d, 16);
      T4[i] = s;
    }
#pragma unroll
    for (int i = 0; i < 4; ++i) {
      float hh = ee[i] / T4[i];
      float hn = z4[i] * hreg[i] + (1.f - z4[i]) * hh;
      hreg[i] = hn;
      unsigned hb = (unsigned short)f2bf(hn);
      unsigned p1 = hb | (((unsigned)__shfl_xor((int)hb, 1, 64)) << 16);
      unsigned long long p2 = (unsigned long long)p1 |
          ((unsigned long long)(unsigned)__shfl_xor((int)p1, 2, 64) << 32);
      if (zlane && (c & 3) == 0) stg8(hAns + rows[i] * 2048 + wbase + c, p2);
      if (zlane) out[(rows[i] * 64 + t) * VD + dim] = hn;
    }
    VMCNT0();
    __syncthreads();
    ans_post(cnt32, 2u * t + 2, w);  // h(t+1) ready
  }
}

// ---------------- launch ----------------
extern "C" void kernel_launch(void* const* d_in, const int* in_sizes, int n_in, void* d_out,
                              int out_size, void* d_ws, size_t ws_size, hipStream_t stream) {
  (void)in_sizes; (void)n_in; (void)out_size;
  if (ws_size < (size_t)WS_NEED) return;

  const int* info = (const int*)d_in[0];
  const int* info_idx = (const int*)d_in[1];
  const int* num_sent = (const int*)d_in[2];
  const int* question = (const int*)d_in[3];
  const int* qidx = (const int*)d_in[4];
  const float* info_emb = (const float*)d_in[5];
  const float* Wi = (const float*)d_in[6];
  const float* Ui = (const float*)d_in[7];
  const float* bi = (const float*)d_in[8];
  const float* q_emb = (const float*)d_in[9];
  const float* Wq = (const float*)d_in[10];
  const float* Uq = (const float*)d_in[11];
  const float* bq = (const float*)d_in[12];
  const float* Wm = (const float*)d_in[13];
  const float* Um = (const float*)d_in[14];
  const float* bm = (const float*)d_in[15];
  const float* Wa = (const float*)d_in[16];
  const float* Ua = (const float*)d_in[17];
  const float* ba = (const float*)d_in[18];

  char* ws = (char*)d_ws;
  unsigned* cnt32 = (unsigned*)(ws + OFF_CNT);
  float* partials = (float*)(ws + OFF_PART);
  unsigned long long* mask = (unsigned long long*)(ws + OFF_MASK);
  float* itab = (float*)(ws + OFF_ITAB);
  float* qtab = (float*)(ws + OFF_QTAB);
  __hip_bfloat16* enc_info = (__hip_bfloat16*)(ws + OFF_EINFO);
  float* enc_q = (float*)(ws + OFF_EQ);
  __hip_bfloat16* prod = (__hip_bfloat16*)(ws + OFF_PROD);
  __hip_bfloat16* hidden = (__hip_bfloat16*)(ws + OFF_HIDDEN);
  short* hA = (short*)(ws + OFF_HA);
  short* hB = (short*)(ws + OFF_HB);
  short* hQA = (short*)(ws + OFF_HQA);
  short* hQB = (short*)(ws + OFF_HQB);
  short* hMA = (short*)(ws + OFF_HMA);
  short* hMB = (short*)(ws + OFF_HMB);
  short* hAns = (short*)(ws + OFF_HANS);

  // zero: stamps+partials+mask; hidden (pad cols); all h exchange buffers
  hipMemsetAsync(ws, 0, OFF_ITAB, stream);
  hipMemsetAsync(ws + OFF_HIDDEN, 0, 128 * 64 * 320 * 2, stream);
  hipMemsetAsync(ws + OFF_HA, 0, WS_NEED - OFF_HA, stream);

  build_tables<<<5100, 256, 0, stream>>>(info_emb, Wi, bi, q_emb, Wq, bq, itab, qtab);
  build_mask<<<32, 256, 0, stream>>>(info_idx, mask);
  scan_rnn<<<160, 192, 0, stream>>>(info, itab, Ui, bi + 1200, mask, enc_info, question, qtab,
                                    Uq, bq + 1200, qidx, enc_q, hA, hB, hQA, hQB, cnt32);
  k_prod<<<13312, 256, 0, stream>>>(enc_info, enc_q, num_sent, prod);
  scan_mem<<<80, 128, 0, stream>>>(prod, Um, Wm, bm, num_sent, hidden, hMA, hMB, cnt32);
  scan_ans<<<250, 512, 0, stream>>>(hidden, Ua, Wa, ba, (float*)d_out, hAns, partials, cnt32);
}